// Round 8
// baseline (268.566 us; speedup 1.0000x reference)
//
#include <hip/hip_runtime.h>
#include <hip/hip_bf16.h>
#include <cstdint>
#include <cstddef>
#include <type_traits>

#define D_MODEL 1024
#define NH      16
#define DH      64
#define LSEQ    2048
#define BATCH   4
#define NTOK    8192      // BATCH * LSEQ
#define K3      3072

typedef __attribute__((ext_vector_type(8))) short  short8;
typedef __attribute__((ext_vector_type(4))) float  floatx4;

__device__ __forceinline__ unsigned short f2bf_bits(float f) {
  __hip_bfloat16 h = __float2bfloat16(f);
  return __builtin_bit_cast(unsigned short, h);
}
__device__ __forceinline__ float bf2f(unsigned short u) {
  return __bfloat162float(__builtin_bit_cast(__hip_bfloat16, u));
}
__device__ __forceinline__ unsigned int pack_bf16(float lo, float hi) {
  return (unsigned int)f2bf_bits(lo) | ((unsigned int)f2bf_bits(hi) << 16);
}

__device__ __forceinline__ void gld_lds16(const void* g, void* l) {
  __builtin_amdgcn_global_load_lds(
      (const __attribute__((address_space(1))) void*)g,
      (__attribute__((address_space(3))) void*)l,
      16, 0, 0);
}

// ---------------------------------------------------------------- fused prologue
// blocks [0,3072): transpose+cast w_qkv [1024][3072] -> wqkvT [3072][1024]
// blocks [3072,4096): transpose+cast w_out [1024][1024] -> woutT
// blocks [4096,6144): LayerNorm(x) -> hbuf (4 tokens/block, wave per token)
// blocks [6144,6176): segment bounds
__global__ __launch_bounds__(256)
void prep_kernel(const float* __restrict__ x, const float* __restrict__ ln_w,
                 const float* __restrict__ ln_b, const float* __restrict__ w_qkv,
                 const float* __restrict__ w_out, const int* __restrict__ sid,
                 __hip_bfloat16* __restrict__ hbuf, __hip_bfloat16* __restrict__ wqkvT,
                 __hip_bfloat16* __restrict__ woutT, int* __restrict__ segstart,
                 int* __restrict__ segend) {
  __shared__ __align__(16) char smem[8448];
  const int blk = blockIdx.x;
  const int tid = threadIdx.x;

  if (blk < 4096) {
    float (*tile)[33] = reinterpret_cast<float(*)[33]>(smem);
    const float* src;  __hip_bfloat16* dst;  int R, C, bx, by;
    if (blk < 3072) { src = w_qkv; dst = wqkvT; R = 1024; C = 3072; bx = blk % 96; by = blk / 96; }
    else            { src = w_out; dst = woutT; R = 1024; C = 1024; bx = (blk - 3072) & 31; by = (blk - 3072) >> 5; }
    const int c0 = bx * 32, r0 = by * 32;
    const int xx = tid & 31, yy = tid >> 5;   // 32 x 8
    #pragma unroll
    for (int j = 0; j < 32; j += 8)
      tile[yy + j][xx] = src[(size_t)(r0 + yy + j) * C + c0 + xx];
    __syncthreads();
    #pragma unroll
    for (int j = 0; j < 32; j += 8)
      dst[(size_t)(c0 + yy + j) * R + r0 + xx] = __float2bfloat16(tile[xx][yy + j]);
  } else if (blk < 6144) {
    const int lane = tid & 63;
    const int t = (blk - 4096) * 4 + (tid >> 6);
    const float4* xr = reinterpret_cast<const float4*>(x) + (size_t)t * 256;
    float4 v[4];
    float s = 0.f, ss = 0.f;
    #pragma unroll
    for (int i = 0; i < 4; i++) {
      v[i] = xr[lane + i * 64];
      s  += (v[i].x + v[i].y) + (v[i].z + v[i].w);
      ss += (v[i].x*v[i].x + v[i].y*v[i].y) + (v[i].z*v[i].z + v[i].w*v[i].w);
    }
    #pragma unroll
    for (int off = 1; off < 64; off <<= 1) {
      s  += __shfl_xor(s, off);
      ss += __shfl_xor(ss, off);
    }
    const float mu = s * (1.f / 1024);
    const float rs = rsqrtf(ss * (1.f / 1024) - mu * mu + 1e-5f);
    const float4* wr = reinterpret_cast<const float4*>(ln_w);
    const float4* br = reinterpret_cast<const float4*>(ln_b);
    ushort4* hr = reinterpret_cast<ushort4*>(hbuf) + (size_t)t * 256;
    #pragma unroll
    for (int i = 0; i < 4; i++) {
      const float4 wv = wr[lane + i * 64];
      const float4 bv = br[lane + i * 64];
      ushort4 o;
      o.x = f2bf_bits((v[i].x - mu) * rs * wv.x + bv.x);
      o.y = f2bf_bits((v[i].y - mu) * rs * wv.y + bv.y);
      o.z = f2bf_bits((v[i].z - mu) * rs * wv.z + bv.z);
      o.w = f2bf_bits((v[i].w - mu) * rs * wv.w + bv.w);
      hr[lane + i * 64] = o;
    }
  } else {
    int* srow = reinterpret_cast<int*>(smem);
    const int sblk = blk - 6144;            // 0..31, 8 per batch
    const int b = sblk >> 3;
    const int* row = sid + (size_t)b * LSEQ;
    #pragma unroll
    for (int i = 0; i < 8; i++) srow[tid + i * 256] = row[tid + i * 256];
    __syncthreads();
    const int l = (sblk & 7) * 256 + tid;
    const int v = srow[l];
    int lo = 0, hi = l;
    while (lo < hi) { int mid = (lo + hi) >> 1; if (srow[mid] < v) lo = mid + 1; else hi = mid; }
    const int i = b * LSEQ + l;
    segstart[i] = lo;
    lo = l + 1; hi = LSEQ;
    while (lo < hi) { int mid = (lo + hi) >> 1; if (srow[mid] <= v) lo = mid + 1; else hi = mid; }
    segend[i] = lo;
  }
}

// ---------------------------------------------------------------- bf16 GEMM, Bt layout
// BK=64, XOR-swizzled LDS (conflict-free). launch_bounds(256,2): measured best.
template <typename OutT>
__global__ __launch_bounds__(256, 2)
void gemm_bt(const __hip_bfloat16* __restrict__ A, const __hip_bfloat16* __restrict__ Bt,
             OutT* __restrict__ C, int M, int N, int K) {
  const int tid  = threadIdx.x;
  const int lane = tid & 63;
  const int wave = tid >> 6;
  const int bm = blockIdx.y * 128;
  const int bn = blockIdx.x * 128;
  const int wm = (wave & 1) * 64;
  const int wn = (wave >> 1) * 64;
  const int quad = lane >> 4;
  const int l16  = lane & 15;

  __shared__ __align__(16) __hip_bfloat16 As[128 * 64];
  __shared__ __align__(16) __hip_bfloat16 Bs[128 * 64];

  floatx4 acc[4][4];
  #pragma unroll
  for (int i = 0; i < 4; i++)
    #pragma unroll
    for (int j = 0; j < 4; j++) {
      floatx4 z = {0.f, 0.f, 0.f, 0.f};
      acc[i][j] = z;
    }

  const int srow = tid >> 3;
  const int sq   = tid & 7;
  const int sc8  = (sq ^ (srow & 7)) * 8;
  const __hip_bfloat16* Ab = A  + (size_t)(bm + srow) * K + sc8;
  const __hip_bfloat16* Bb = Bt + (size_t)(bn + srow) * K + sc8;

  const int axr = l16 & 7;

  for (int k0 = 0; k0 < K; k0 += 64) {
    __syncthreads();
    #pragma unroll
    for (int p = 0; p < 4; p++) {
      gld_lds16(Ab + (size_t)(p * 32) * K + k0, (char*)As + p * 4096 + tid * 16);
      gld_lds16(Bb + (size_t)(p * 32) * K + k0, (char*)Bs + p * 4096 + tid * 16);
    }
    __syncthreads();
    #pragma unroll
    for (int s0 = 0; s0 < 2; s0++) {
      const int qo = ((s0 * 4 + quad) ^ axr) * 8;
      short8 af[4], bfr[4];
      #pragma unroll
      for (int i = 0; i < 4; i++)
        af[i] = *reinterpret_cast<const short8*>(As + (wm + i * 16 + l16) * 64 + qo);
      #pragma unroll
      for (int j = 0; j < 4; j++)
        bfr[j] = *reinterpret_cast<const short8*>(Bs + (wn + j * 16 + l16) * 64 + qo);
      #pragma unroll
      for (int i = 0; i < 4; i++)
        #pragma unroll
        for (int j = 0; j < 4; j++)
          acc[i][j] = __builtin_amdgcn_mfma_f32_16x16x32_bf16(af[i], bfr[j], acc[i][j], 0, 0, 0);
    }
  }

  #pragma unroll
  for (int i = 0; i < 4; i++)
    #pragma unroll
    for (int j = 0; j < 4; j++) {
      const int row0 = bm + wm + i * 16 + quad * 4;
      const int col  = bn + wn + j * 16 + l16;
      #pragma unroll
      for (int r = 0; r < 4; r++) {
        if constexpr (std::is_same<OutT, __hip_bfloat16>::value)
          C[(size_t)(row0 + r) * N + col] = __float2bfloat16(acc[i][j][r]);
        else
          C[(size_t)(row0 + r) * N + col] = acc[i][j][r];
      }
    }
}

// ---------------------------------------------------------------- fused rope + vtrans
__global__ __launch_bounds__(256)
void ropevt_kernel(const unsigned short* __restrict__ qkv, const float* __restrict__ qw,
                   const float* __restrict__ kw, unsigned short* __restrict__ qT,
                   unsigned short* __restrict__ kT, unsigned short* __restrict__ vT) {
  __shared__ __align__(16) unsigned short T[64 * 64];
  const int blk = blockIdx.x;
  const int tid = threadIdx.x;

  if (blk < 2048) {
    const int lane = tid & 63;
    const int t = blk * 4 + (tid >> 6);
    const int b = t >> 11, l = t & 2047;
    const unsigned short* row = qkv + (size_t)t * K3;
    const int hh = lane >> 2;
    const int jb = (lane & 3) * 8;
    const int base = hh * 64 + jb;

    const short8 qa_u = *reinterpret_cast<const short8*>(row + base);
    const short8 qb_u = *reinterpret_cast<const short8*>(row + base + 32);
    const short8 ka_u = *reinterpret_cast<const short8*>(row + 1024 + base);
    const short8 kb_u = *reinterpret_cast<const short8*>(row + 1024 + base + 32);

    float qa[8], qb[8], ka[8], kb[8];
    float s_q = 0.f, ss_q = 0.f, s_k = 0.f, ss_k = 0.f;
    #pragma unroll
    for (int e = 0; e < 8; e++) {
      qa[e] = bf2f((unsigned short)qa_u[e]); qb[e] = bf2f((unsigned short)qb_u[e]);
      ka[e] = bf2f((unsigned short)ka_u[e]); kb[e] = bf2f((unsigned short)kb_u[e]);
      s_q  += qa[e] + qb[e];  ss_q += qa[e]*qa[e] + qb[e]*qb[e];
      s_k  += ka[e] + kb[e];  ss_k += ka[e]*ka[e] + kb[e]*kb[e];
    }
    #pragma unroll
    for (int off = 1; off < 64; off <<= 1) {
      s_q  += __shfl_xor(s_q, off);  ss_q += __shfl_xor(ss_q, off);
      s_k  += __shfl_xor(s_k, off);  ss_k += __shfl_xor(ss_k, off);
    }
    const float qmu = s_q * (1.f/1024);
    const float qrs = rsqrtf(ss_q * (1.f/1024) - qmu*qmu + 1e-5f);
    const float kmu = s_k * (1.f/1024);
    const float krs = rsqrtf(ss_k * (1.f/1024) - kmu*kmu + 1e-5f);

    const int j0 = lane & 31;
    const float invf = __expf(-(float)j0 * 0.28782313662425575f);   // ln(1e4)/32
    float tsin, tcos;
    sincosf((float)l * invf, &tsin, &tcos);

    const float4 wq0 = *reinterpret_cast<const float4*>(qw + base);
    const float4 wq1 = *reinterpret_cast<const float4*>(qw + base + 4);
    const float4 wq2 = *reinterpret_cast<const float4*>(qw + base + 32);
    const float4 wq3 = *reinterpret_cast<const float4*>(qw + base + 36);
    const float4 wk0 = *reinterpret_cast<const float4*>(kw + base);
    const float4 wk1 = *reinterpret_cast<const float4*>(kw + base + 4);
    const float4 wk2 = *reinterpret_cast<const float4*>(kw + base + 32);
    const float4 wk3 = *reinterpret_cast<const float4*>(kw + base + 36);
    const float wqa[8] = {wq0.x,wq0.y,wq0.z,wq0.w, wq1.x,wq1.y,wq1.z,wq1.w};
    const float wqb[8] = {wq2.x,wq2.y,wq2.z,wq2.w, wq3.x,wq3.y,wq3.z,wq3.w};
    const float wka[8] = {wk0.x,wk0.y,wk0.z,wk0.w, wk1.x,wk1.y,wk1.z,wk1.w};
    const float wkb[8] = {wk2.x,wk2.y,wk2.z,wk2.w, wk3.x,wk3.y,wk3.z,wk3.w};

    short8 oqa, oqb, oka, okb;
    #pragma unroll
    for (int e = 0; e < 8; e++) {
      const int j = jb + e;
      const float c  = __shfl(tcos, j);
      const float sn = __shfl(tsin, j);
      const float qn1 = (qa[e] - qmu) * qrs * wqa[e];
      const float qn2 = (qb[e] - qmu) * qrs * wqb[e];
      const float kn1 = (ka[e] - kmu) * krs * wka[e];
      const float kn2 = (kb[e] - kmu) * krs * wkb[e];
      oqa[e] = (short)f2bf_bits((qn1 * c - qn2 * sn) * 0.125f);
      oqb[e] = (short)f2bf_bits((qn2 * c + qn1 * sn) * 0.125f);
      oka[e] = (short)f2bf_bits(kn1 * c - kn2 * sn);
      okb[e] = (short)f2bf_bits(kn2 * c + kn1 * sn);
    }
    const size_t ob = ((size_t)(b * NH + hh) * LSEQ + l) * DH + jb;
    *reinterpret_cast<short8*>(qT + ob)      = oqa;
    *reinterpret_cast<short8*>(qT + ob + 32) = oqb;
    *reinterpret_cast<short8*>(kT + ob)      = oka;
    *reinterpret_cast<short8*>(kT + ob + 32) = okb;
  } else {
    const int blkv = blk - 2048;
    const int l0 = (blkv & 31) * 64;
    const int bh = blkv >> 5;
    const int b = bh >> 4, h = bh & 15;
    const int sr = tid >> 3, scc = tid & 7;
    const int r1 = sr + 32;
    gld_lds16(qkv + (size_t)(b * LSEQ + l0 + sr) * K3 + 2048 + h * 64 + ((scc ^ ((sr >> 3) & 7)) * 8),
              (char*)T + tid * 16);
    gld_lds16(qkv + (size_t)(b * LSEQ + l0 + r1) * K3 + 2048 + h * 64 + ((scc ^ ((r1 >> 3) & 7)) * 8),
              (char*)T + 4096 + tid * 16);
    __syncthreads();
    #pragma unroll
    for (int it = 0; it < 2; it++) {
      const int cid = tid + it * 256;
      const int dh = cid >> 3, c = (cid & 7) * 8;
      const int sl = (dh >> 3) ^ ((c >> 3) & 7);
      short8 o;
      #pragma unroll
      for (int e = 0; e < 8; e++)
        o[e] = (short)T[(c + e) * 64 + sl * 8 + (dh & 7)];
      *reinterpret_cast<short8*>(vT + ((size_t)bh * DH + dh) * LSEQ + l0 + c) = o;
    }
  }
}

// ---------------------------------------------------------------- MFMA flash attention
// 2-way K-SPLIT flash attention (flash-decoding style), 512 threads / 8 waves.
// Wave pair (2p, 2p+1) shares query group p (32 queries): even wave processes
// even 64-key tiles, odd wave the odd tiles; each keeps independent watermark
// online-softmax state; one LDS exchange + single __syncthreads merges the
// pair exactly at the end. K/V read direct from global (L2-resident).
// r7 resubmission (r7 bench died harness-side, no kernel signal). vs r5: only
// the launch bound changed — r5's __launch_bounds__(512,4) forced VGPR=64
// (body needs ~110) -> catastrophic scratch spills (WRITE_SIZE 16->357 MB).
// Compiler-chosen allocation + 74.7 KB LDS gives 2 blocks/CU = 16 waves/CU
// with HALF the per-wave tile count of the lockstep kernel -> attacks the
// measured per-wave-serial-latency wall. Prologue K-load now guarded
// (empty-span waves skip it).
__global__ __launch_bounds__(512)
void attn_mfma(const unsigned short* __restrict__ qT, const unsigned short* __restrict__ kT,
               const unsigned short* __restrict__ vT, const int* __restrict__ segs,
               const int* __restrict__ sege, unsigned short* __restrict__ ctx) {
  const int tid  = threadIdx.x;
  const int lane = tid & 63, w = tid >> 6;      // w in [0,8)
  const int pair = w >> 1, half = w & 1;        // query group / K parity
  const int quad = lane >> 4, l16 = lane & 15;

  const int qbase = blockIdx.x * 128;
  const int h = blockIdx.y, b = blockIdx.z;
  const size_t bh = (size_t)(b * NH + h);
  const unsigned short* Kg = kT + bh * LSEQ * DH;
  const unsigned short* Vg = vT + bh * DH * LSEQ;

  __shared__ __align__(16) unsigned short Ps[8][32 * 72];
  __shared__ __align__(16) float MB[4 * 64 * 37];   // odd-wave state for merge

  const int qg = qbase + pair * 32;

  short8 qf[2][2];
  int st[2], en[2], gmin[2], gmax[2];
  #pragma unroll
  for (int g = 0; g < 2; g++) {
    const int qy = qg + g * 16 + l16;
    const unsigned short* Qrow = qT + (bh * LSEQ + qy) * DH;
    qf[g][0] = *reinterpret_cast<const short8*>(Qrow + quad * 8);
    qf[g][1] = *reinterpret_cast<const short8*>(Qrow + 32 + quad * 8);
    st[g] = segs[b * LSEQ + qy];
    en[g] = sege[b * LSEQ + qy];
    gmin[g] = segs[b * LSEQ + qg + g * 16];
    gmax[g] = sege[b * LSEQ + qg + g * 16 + 15];
  }
  const int wstart = (gmin[0] & ~63) + half * 64;  // this wave's first tile
  const int wmax   = gmax[1];

  floatx4 acc[2][4];
  #pragma unroll
  for (int g = 0; g < 2; g++)
    #pragma unroll
    for (int dt = 0; dt < 4; dt++) { floatx4 z = {0.f,0.f,0.f,0.f}; acc[g][dt] = z; }
  float m[2] = {9.f, 9.f};          // watermark; rare path handles exceedance
  float lsum[2] = {0.f, 0.f};       // per-lane partials; quad-reduced before merge

  // prologue: K fragments for first tile (guarded: empty-span waves skip)
  short8 kf[4][2];
  if (wstart < wmax) {
    #pragma unroll
    for (int t = 0; t < 4; t++) {
      const unsigned short* kp = Kg + (size_t)(wstart + t * 16 + l16) * DH + quad * 8;
      kf[t][0] = *reinterpret_cast<const short8*>(kp);
      kf[t][1] = *reinterpret_cast<const short8*>(kp + 32);
    }
  }

  for (int kk = wstart; kk < wmax; kk += 128) {   // stride 2 tiles (K-split)
    const bool have_next = (kk + 128) < wmax;

    // V loads for THIS tile first (PV waits on these)
    short8 vf[4][2];
    #pragma unroll
    for (int dt = 0; dt < 4; dt++) {
      const unsigned short* vp = Vg + (size_t)(dt * 16 + l16) * LSEQ + kk + quad * 8;
      vf[dt][0] = *reinterpret_cast<const short8*>(vp);
      vf[dt][1] = *reinterpret_cast<const short8*>(vp + 32);
    }
    // next tile's K prefetch (PV's vmcnt wait leaves these in flight)
    short8 kn[4][2];
    if (have_next) {
      #pragma unroll
      for (int t = 0; t < 4; t++) {
        const unsigned short* kp = Kg + (size_t)(kk + 128 + t * 16 + l16) * DH + quad * 8;
        kn[t][0] = *reinterpret_cast<const short8*>(kp);
        kn[t][1] = *reinterpret_cast<const short8*>(kp + 32);
      }
    }

    bool act[2];
    #pragma unroll
    for (int g = 0; g < 2; g++)
      act[g] = !(kk + 64 <= gmin[g] || kk >= gmax[g]);

    #pragma unroll
    for (int g = 0; g < 2; g++) {
      if (!act[g]) continue;

      floatx4 sc[4];
      __builtin_amdgcn_s_setprio(1);
      #pragma unroll
      for (int t = 0; t < 4; t++) {
        floatx4 z = {0.f,0.f,0.f,0.f};
        sc[t] = __builtin_amdgcn_mfma_f32_16x16x32_bf16(kf[t][0], qf[g][0], z, 0, 0, 0);
        sc[t] = __builtin_amdgcn_mfma_f32_16x16x32_bf16(kf[t][1], qf[g][1], sc[t], 0, 0, 0);
      }
      __builtin_amdgcn_s_setprio(0);

      const unsigned span = (unsigned)(en[g] - st[g]);
      float vm = -1e30f;
      #pragma unroll
      for (int t = 0; t < 4; t++) {
        const int k0 = kk + t * 16 + quad * 4;
        #pragma unroll
        for (int r = 0; r < 4; r++) {
          const bool ok = (unsigned)(k0 + r - st[g]) < span;
          sc[t][r] = ok ? sc[t][r] : -1e30f;
          vm = fmaxf(vm, sc[t][r]);
        }
      }

      if (__any(vm > m[g])) {        // rare: watermark exceeded -> full rescale
        float vv = fmaxf(vm, __shfl_xor(vm, 16));
        vv = fmaxf(vv, __shfl_xor(vv, 32));
        const float a = __expf(m[g] - vv);
        lsum[g] *= a;
        #pragma unroll
        for (int dt = 0; dt < 4; dt++)
          #pragma unroll
          for (int r = 0; r < 4; r++) acc[g][dt][r] *= a;
        m[g] = vv;
      }

      const float mn = m[g];
      float rs = 0.f;
      #pragma unroll
      for (int t = 0; t < 4; t++) {
        const float p0 = __expf(sc[t][0] - mn);   // exp(-1e30-mn)==0: masked
        const float p1 = __expf(sc[t][1] - mn);
        const float p2 = __expf(sc[t][2] - mn);
        const float p3 = __expf(sc[t][3] - mn);
        rs += (p0 + p1) + (p2 + p3);
        uint2 pk;
        pk.x = pack_bf16(p0, p1);
        pk.y = pack_bf16(p2, p3);
        *reinterpret_cast<uint2*>(&Ps[w][(g * 16 + l16) * 72 + t * 16 + quad * 4]) = pk;
      }
      lsum[g] += rs;
    }

    short8 pf[2][2];
    #pragma unroll
    for (int g = 0; g < 2; g++) {
      if (!act[g]) continue;
      pf[g][0] = *reinterpret_cast<const short8*>(&Ps[w][(g * 16 + l16) * 72 + quad * 8]);
      pf[g][1] = *reinterpret_cast<const short8*>(&Ps[w][(g * 16 + l16) * 72 + 32 + quad * 8]);
    }
    __builtin_amdgcn_s_setprio(1);
    #pragma unroll
    for (int dt = 0; dt < 4; dt++) {
      #pragma unroll
      for (int g = 0; g < 2; g++) {
        if (!act[g]) continue;
        acc[g][dt] = __builtin_amdgcn_mfma_f32_16x16x32_bf16(vf[dt][0], pf[g][0], acc[g][dt], 0, 0, 0);
        acc[g][dt] = __builtin_amdgcn_mfma_f32_16x16x32_bf16(vf[dt][1], pf[g][1], acc[g][dt], 0, 0, 0);
      }
    }
    __builtin_amdgcn_s_setprio(0);

    if (have_next) {
      #pragma unroll
      for (int t = 0; t < 4; t++) {
        kf[t][0] = kn[t][0];
        kf[t][1] = kn[t][1];
      }
    }
  }

  // quad-reduce lsum partials (both halves; needed for exact merge)
  #pragma unroll
  for (int g = 0; g < 2; g++) {
    lsum[g] += __shfl_xor(lsum[g], 16);
    lsum[g] += __shfl_xor(lsum[g], 32);
  }

  // ---- merge the K-split pair (odd -> LDS, sync, even combines & writes) ----
  float* mb = MB + ((size_t)(pair * 64 + lane)) * 37;
  if (half) {
    #pragma unroll
    for (int g = 0; g < 2; g++)
      #pragma unroll
      for (int dt = 0; dt < 4; dt++)
        #pragma unroll
        for (int r = 0; r < 4; r++)
          mb[g * 16 + dt * 4 + r] = acc[g][dt][r];
    mb[32] = m[0];  mb[33] = m[1];
    mb[34] = lsum[0]; mb[35] = lsum[1];
  }
  __syncthreads();
  if (!half) {
    #pragma unroll
    for (int g = 0; g < 2; g++) {
      const float Mo = mb[32 + g];
      const float Lo = mb[34 + g];
      const float Mm = fmaxf(m[g], Mo);
      const float we = __expf(m[g] - Mm);
      const float wo = __expf(Mo - Mm);
      const float L  = lsum[g] * we + Lo * wo;
      const float inv = (L > 0.f) ? 1.f / L : 0.f;
      const float fe = we * inv, fo = wo * inv;
      const int qy = qg + g * 16 + l16;
      unsigned short* orow = ctx + ((size_t)(b * LSEQ + qy)) * D_MODEL + h * DH;
      #pragma unroll
      for (int dt = 0; dt < 4; dt++) {
        const float o0 = acc[g][dt][0] * fe + mb[g * 16 + dt * 4 + 0] * fo;
        const float o1 = acc[g][dt][1] * fe + mb[g * 16 + dt * 4 + 1] * fo;
        const float o2 = acc[g][dt][2] * fe + mb[g * 16 + dt * 4 + 2] * fo;
        const float o3 = acc[g][dt][3] * fe + mb[g * 16 + dt * 4 + 3] * fo;
        uint2 o;
        o.x = pack_bf16(o0, o1);
        o.y = pack_bf16(o2, o3);
        *reinterpret_cast<uint2*>(orow + dt * 16 + quad * 4) = o;
      }
    }
  }
}

// ---------------------------------------------------------------- launch
extern "C" void kernel_launch(void* const* d_in, const int* in_sizes, int n_in,
                              void* d_out, int out_size, void* d_ws, size_t ws_size,
                              hipStream_t stream) {
  const float* x      = (const float*)d_in[0];
  const int*   sid    = (const int*)d_in[1];
  const float* ln_w   = (const float*)d_in[2];
  const float* ln_b   = (const float*)d_in[3];
  const float* w_qkv  = (const float*)d_in[4];
  const float* q_ln_w = (const float*)d_in[5];
  const float* k_ln_w = (const float*)d_in[6];
  const float* w_out  = (const float*)d_in[7];
  float* out = (float*)d_out;
  char* ws = (char*)d_ws;

  constexpr size_t OFF_WQKVT = 0;                        //  6,291,456
  constexpr size_t OFF_WOUTT = 6291456;                  //  2,097,152
  constexpr size_t OFF_H     = 8388608;                  // 16,777,216
  constexpr size_t OFF_QKV   = 25165824;                 // 50,331,648 (bf16)
  constexpr size_t OFF_QT    = 75497472;                 // 16,777,216
  constexpr size_t OFF_KT    = 92274688;                 // 16,777,216
  constexpr size_t OFF_VT    = 109051904;                // 16,777,216
  constexpr size_t OFF_CTX   = 125829120;                // 16,777,216
  constexpr size_t OFF_SEGS  = 142606336;                // 32,768
  constexpr size_t OFF_SEGE  = 142639104;                // 32,768

  __hip_bfloat16* wqkvT = (__hip_bfloat16*)(ws + OFF_WQKVT);
  __hip_bfloat16* woutT = (__hip_bfloat16*)(ws + OFF_WOUTT);
  __hip_bfloat16* hbuf  = (__hip_bfloat16*)(ws + OFF_H);
  __hip_bfloat16* qkvb  = (__hip_bfloat16*)(ws + OFF_QKV);
  unsigned short* qTb   = (unsigned short*)(ws + OFF_QT);
  unsigned short* kTb   = (unsigned short*)(ws + OFF_KT);
  unsigned short* vTb   = (unsigned short*)(ws + OFF_VT);
  unsigned short* ctx   = (unsigned short*)(ws + OFF_CTX);
  int*            segst = (int*)(ws + OFF_SEGS);
  int*            segen = (int*)(ws + OFF_SEGE);

  prep_kernel<<<6176, 256, 0, stream>>>(x, ln_w, ln_b, w_qkv, w_out, sid,
                                        hbuf, wqkvT, woutT, segst, segen);
  gemm_bt<__hip_bfloat16><<<dim3(K3 / 128, NTOK / 128), 256, 0, stream>>>(
      hbuf, wqkvT, qkvb, NTOK, K3, 1024);
  ropevt_kernel<<<4096, 256, 0, stream>>>((const unsigned short*)qkvb, q_ln_w, k_ln_w,
                                          qTb, kTb, vTb);
  attn_mfma<<<dim3(LSEQ / 128, NH, BATCH), 512, 0, stream>>>(qTb, kTb, vTb, segst, segen, ctx);
  gemm_bt<float><<<dim3(D_MODEL / 128, NTOK / 128), 256, 0, stream>>>(
      (const __hip_bfloat16*)ctx, woutT, out, NTOK, D_MODEL, 1024);
}

// Round 9
// 250.836 us; speedup vs baseline: 1.0707x; 1.0707x over previous
//
#include <hip/hip_runtime.h>
#include <hip/hip_bf16.h>
#include <cstdint>
#include <cstddef>
#include <type_traits>

#define D_MODEL 1024
#define NH      16
#define DH      64
#define LSEQ    2048
#define BATCH   4
#define NTOK    8192      // BATCH * LSEQ
#define K3      3072

typedef __attribute__((ext_vector_type(8))) short  short8;
typedef __attribute__((ext_vector_type(4))) float  floatx4;

__device__ __forceinline__ unsigned short f2bf_bits(float f) {
  __hip_bfloat16 h = __float2bfloat16(f);
  return __builtin_bit_cast(unsigned short, h);
}
__device__ __forceinline__ float bf2f(unsigned short u) {
  return __bfloat162float(__builtin_bit_cast(__hip_bfloat16, u));
}
__device__ __forceinline__ unsigned int pack_bf16(float lo, float hi) {
  return (unsigned int)f2bf_bits(lo) | ((unsigned int)f2bf_bits(hi) << 16);
}

__device__ __forceinline__ void gld_lds16(const void* g, void* l) {
  __builtin_amdgcn_global_load_lds(
      (const __attribute__((address_space(1))) void*)g,
      (__attribute__((address_space(3))) void*)l,
      16, 0, 0);
}

// ---------------------------------------------------------------- fused prologue
// blocks [0,3072): transpose+cast w_qkv [1024][3072] -> wqkvT [3072][1024]
// blocks [3072,4096): transpose+cast w_out [1024][1024] -> woutT
// blocks [4096,6144): LayerNorm(x) -> hbuf (4 tokens/block, wave per token)
// blocks [6144,6176): segment bounds
__global__ __launch_bounds__(256)
void prep_kernel(const float* __restrict__ x, const float* __restrict__ ln_w,
                 const float* __restrict__ ln_b, const float* __restrict__ w_qkv,
                 const float* __restrict__ w_out, const int* __restrict__ sid,
                 __hip_bfloat16* __restrict__ hbuf, __hip_bfloat16* __restrict__ wqkvT,
                 __hip_bfloat16* __restrict__ woutT, int* __restrict__ segstart,
                 int* __restrict__ segend) {
  __shared__ __align__(16) char smem[8448];
  const int blk = blockIdx.x;
  const int tid = threadIdx.x;

  if (blk < 4096) {
    float (*tile)[33] = reinterpret_cast<float(*)[33]>(smem);
    const float* src;  __hip_bfloat16* dst;  int R, C, bx, by;
    if (blk < 3072) { src = w_qkv; dst = wqkvT; R = 1024; C = 3072; bx = blk % 96; by = blk / 96; }
    else            { src = w_out; dst = woutT; R = 1024; C = 1024; bx = (blk - 3072) & 31; by = (blk - 3072) >> 5; }
    const int c0 = bx * 32, r0 = by * 32;
    const int xx = tid & 31, yy = tid >> 5;   // 32 x 8
    #pragma unroll
    for (int j = 0; j < 32; j += 8)
      tile[yy + j][xx] = src[(size_t)(r0 + yy + j) * C + c0 + xx];
    __syncthreads();
    #pragma unroll
    for (int j = 0; j < 32; j += 8)
      dst[(size_t)(c0 + yy + j) * R + r0 + xx] = __float2bfloat16(tile[xx][yy + j]);
  } else if (blk < 6144) {
    const int lane = tid & 63;
    const int t = (blk - 4096) * 4 + (tid >> 6);
    const float4* xr = reinterpret_cast<const float4*>(x) + (size_t)t * 256;
    float4 v[4];
    float s = 0.f, ss = 0.f;
    #pragma unroll
    for (int i = 0; i < 4; i++) {
      v[i] = xr[lane + i * 64];
      s  += (v[i].x + v[i].y) + (v[i].z + v[i].w);
      ss += (v[i].x*v[i].x + v[i].y*v[i].y) + (v[i].z*v[i].z + v[i].w*v[i].w);
    }
    #pragma unroll
    for (int off = 1; off < 64; off <<= 1) {
      s  += __shfl_xor(s, off);
      ss += __shfl_xor(ss, off);
    }
    const float mu = s * (1.f / 1024);
    const float rs = rsqrtf(ss * (1.f / 1024) - mu * mu + 1e-5f);
    const float4* wr = reinterpret_cast<const float4*>(ln_w);
    const float4* br = reinterpret_cast<const float4*>(ln_b);
    ushort4* hr = reinterpret_cast<ushort4*>(hbuf) + (size_t)t * 256;
    #pragma unroll
    for (int i = 0; i < 4; i++) {
      const float4 wv = wr[lane + i * 64];
      const float4 bv = br[lane + i * 64];
      ushort4 o;
      o.x = f2bf_bits((v[i].x - mu) * rs * wv.x + bv.x);
      o.y = f2bf_bits((v[i].y - mu) * rs * wv.y + bv.y);
      o.z = f2bf_bits((v[i].z - mu) * rs * wv.z + bv.z);
      o.w = f2bf_bits((v[i].w - mu) * rs * wv.w + bv.w);
      hr[lane + i * 64] = o;
    }
  } else {
    int* srow = reinterpret_cast<int*>(smem);
    const int sblk = blk - 6144;            // 0..31, 8 per batch
    const int b = sblk >> 3;
    const int* row = sid + (size_t)b * LSEQ;
    #pragma unroll
    for (int i = 0; i < 8; i++) srow[tid + i * 256] = row[tid + i * 256];
    __syncthreads();
    const int l = (sblk & 7) * 256 + tid;
    const int v = srow[l];
    int lo = 0, hi = l;
    while (lo < hi) { int mid = (lo + hi) >> 1; if (srow[mid] < v) lo = mid + 1; else hi = mid; }
    const int i = b * LSEQ + l;
    segstart[i] = lo;
    lo = l + 1; hi = LSEQ;
    while (lo < hi) { int mid = (lo + hi) >> 1; if (srow[mid] <= v) lo = mid + 1; else hi = mid; }
    segend[i] = lo;
  }
}

// ---------------------------------------------------------------- bf16 GEMM, Bt layout
// BK=64, XOR-swizzled LDS (conflict-free). launch_bounds(256,2): measured best.
template <typename OutT>
__global__ __launch_bounds__(256, 2)
void gemm_bt(const __hip_bfloat16* __restrict__ A, const __hip_bfloat16* __restrict__ Bt,
             OutT* __restrict__ C, int M, int N, int K) {
  const int tid  = threadIdx.x;
  const int lane = tid & 63;
  const int wave = tid >> 6;
  const int bm = blockIdx.y * 128;
  const int bn = blockIdx.x * 128;
  const int wm = (wave & 1) * 64;
  const int wn = (wave >> 1) * 64;
  const int quad = lane >> 4;
  const int l16  = lane & 15;

  __shared__ __align__(16) __hip_bfloat16 As[128 * 64];
  __shared__ __align__(16) __hip_bfloat16 Bs[128 * 64];

  floatx4 acc[4][4];
  #pragma unroll
  for (int i = 0; i < 4; i++)
    #pragma unroll
    for (int j = 0; j < 4; j++) {
      floatx4 z = {0.f, 0.f, 0.f, 0.f};
      acc[i][j] = z;
    }

  const int srow = tid >> 3;
  const int sq   = tid & 7;
  const int sc8  = (sq ^ (srow & 7)) * 8;
  const __hip_bfloat16* Ab = A  + (size_t)(bm + srow) * K + sc8;
  const __hip_bfloat16* Bb = Bt + (size_t)(bn + srow) * K + sc8;

  const int axr = l16 & 7;

  for (int k0 = 0; k0 < K; k0 += 64) {
    __syncthreads();
    #pragma unroll
    for (int p = 0; p < 4; p++) {
      gld_lds16(Ab + (size_t)(p * 32) * K + k0, (char*)As + p * 4096 + tid * 16);
      gld_lds16(Bb + (size_t)(p * 32) * K + k0, (char*)Bs + p * 4096 + tid * 16);
    }
    __syncthreads();
    #pragma unroll
    for (int s0 = 0; s0 < 2; s0++) {
      const int qo = ((s0 * 4 + quad) ^ axr) * 8;
      short8 af[4], bfr[4];
      #pragma unroll
      for (int i = 0; i < 4; i++)
        af[i] = *reinterpret_cast<const short8*>(As + (wm + i * 16 + l16) * 64 + qo);
      #pragma unroll
      for (int j = 0; j < 4; j++)
        bfr[j] = *reinterpret_cast<const short8*>(Bs + (wn + j * 16 + l16) * 64 + qo);
      #pragma unroll
      for (int i = 0; i < 4; i++)
        #pragma unroll
        for (int j = 0; j < 4; j++)
          acc[i][j] = __builtin_amdgcn_mfma_f32_16x16x32_bf16(af[i], bfr[j], acc[i][j], 0, 0, 0);
    }
  }

  #pragma unroll
  for (int i = 0; i < 4; i++)
    #pragma unroll
    for (int j = 0; j < 4; j++) {
      const int row0 = bm + wm + i * 16 + quad * 4;
      const int col  = bn + wn + j * 16 + l16;
      #pragma unroll
      for (int r = 0; r < 4; r++) {
        if constexpr (std::is_same<OutT, __hip_bfloat16>::value)
          C[(size_t)(row0 + r) * N + col] = __float2bfloat16(acc[i][j][r]);
        else
          C[(size_t)(row0 + r) * N + col] = acc[i][j][r];
      }
    }
}

// ---------------------------------------------------------------- fused rope + vtrans
__global__ __launch_bounds__(256)
void ropevt_kernel(const unsigned short* __restrict__ qkv, const float* __restrict__ qw,
                   const float* __restrict__ kw, unsigned short* __restrict__ qT,
                   unsigned short* __restrict__ kT, unsigned short* __restrict__ vT) {
  __shared__ __align__(16) unsigned short T[64 * 64];
  const int blk = blockIdx.x;
  const int tid = threadIdx.x;

  if (blk < 2048) {
    const int lane = tid & 63;
    const int t = blk * 4 + (tid >> 6);
    const int b = t >> 11, l = t & 2047;
    const unsigned short* row = qkv + (size_t)t * K3;
    const int hh = lane >> 2;
    const int jb = (lane & 3) * 8;
    const int base = hh * 64 + jb;

    const short8 qa_u = *reinterpret_cast<const short8*>(row + base);
    const short8 qb_u = *reinterpret_cast<const short8*>(row + base + 32);
    const short8 ka_u = *reinterpret_cast<const short8*>(row + 1024 + base);
    const short8 kb_u = *reinterpret_cast<const short8*>(row + 1024 + base + 32);

    float qa[8], qb[8], ka[8], kb[8];
    float s_q = 0.f, ss_q = 0.f, s_k = 0.f, ss_k = 0.f;
    #pragma unroll
    for (int e = 0; e < 8; e++) {
      qa[e] = bf2f((unsigned short)qa_u[e]); qb[e] = bf2f((unsigned short)qb_u[e]);
      ka[e] = bf2f((unsigned short)ka_u[e]); kb[e] = bf2f((unsigned short)kb_u[e]);
      s_q  += qa[e] + qb[e];  ss_q += qa[e]*qa[e] + qb[e]*qb[e];
      s_k  += ka[e] + kb[e];  ss_k += ka[e]*ka[e] + kb[e]*kb[e];
    }
    #pragma unroll
    for (int off = 1; off < 64; off <<= 1) {
      s_q  += __shfl_xor(s_q, off);  ss_q += __shfl_xor(ss_q, off);
      s_k  += __shfl_xor(s_k, off);  ss_k += __shfl_xor(ss_k, off);
    }
    const float qmu = s_q * (1.f/1024);
    const float qrs = rsqrtf(ss_q * (1.f/1024) - qmu*qmu + 1e-5f);
    const float kmu = s_k * (1.f/1024);
    const float krs = rsqrtf(ss_k * (1.f/1024) - kmu*kmu + 1e-5f);

    const int j0 = lane & 31;
    const float invf = __expf(-(float)j0 * 0.28782313662425575f);   // ln(1e4)/32
    float tsin, tcos;
    sincosf((float)l * invf, &tsin, &tcos);

    const float4 wq0 = *reinterpret_cast<const float4*>(qw + base);
    const float4 wq1 = *reinterpret_cast<const float4*>(qw + base + 4);
    const float4 wq2 = *reinterpret_cast<const float4*>(qw + base + 32);
    const float4 wq3 = *reinterpret_cast<const float4*>(qw + base + 36);
    const float4 wk0 = *reinterpret_cast<const float4*>(kw + base);
    const float4 wk1 = *reinterpret_cast<const float4*>(kw + base + 4);
    const float4 wk2 = *reinterpret_cast<const float4*>(kw + base + 32);
    const float4 wk3 = *reinterpret_cast<const float4*>(kw + base + 36);
    const float wqa[8] = {wq0.x,wq0.y,wq0.z,wq0.w, wq1.x,wq1.y,wq1.z,wq1.w};
    const float wqb[8] = {wq2.x,wq2.y,wq2.z,wq2.w, wq3.x,wq3.y,wq3.z,wq3.w};
    const float wka[8] = {wk0.x,wk0.y,wk0.z,wk0.w, wk1.x,wk1.y,wk1.z,wk1.w};
    const float wkb[8] = {wk2.x,wk2.y,wk2.z,wk2.w, wk3.x,wk3.y,wk3.z,wk3.w};

    short8 oqa, oqb, oka, okb;
    #pragma unroll
    for (int e = 0; e < 8; e++) {
      const int j = jb + e;
      const float c  = __shfl(tcos, j);
      const float sn = __shfl(tsin, j);
      const float qn1 = (qa[e] - qmu) * qrs * wqa[e];
      const float qn2 = (qb[e] - qmu) * qrs * wqb[e];
      const float kn1 = (ka[e] - kmu) * krs * wka[e];
      const float kn2 = (kb[e] - kmu) * krs * wkb[e];
      oqa[e] = (short)f2bf_bits((qn1 * c - qn2 * sn) * 0.125f);
      oqb[e] = (short)f2bf_bits((qn2 * c + qn1 * sn) * 0.125f);
      oka[e] = (short)f2bf_bits(kn1 * c - kn2 * sn);
      okb[e] = (short)f2bf_bits(kn2 * c + kn1 * sn);
    }
    const size_t ob = ((size_t)(b * NH + hh) * LSEQ + l) * DH + jb;
    *reinterpret_cast<short8*>(qT + ob)      = oqa;
    *reinterpret_cast<short8*>(qT + ob + 32) = oqb;
    *reinterpret_cast<short8*>(kT + ob)      = oka;
    *reinterpret_cast<short8*>(kT + ob + 32) = okb;
  } else {
    const int blkv = blk - 2048;
    const int l0 = (blkv & 31) * 64;
    const int bh = blkv >> 5;
    const int b = bh >> 4, h = bh & 15;
    const int sr = tid >> 3, scc = tid & 7;
    const int r1 = sr + 32;
    gld_lds16(qkv + (size_t)(b * LSEQ + l0 + sr) * K3 + 2048 + h * 64 + ((scc ^ ((sr >> 3) & 7)) * 8),
              (char*)T + tid * 16);
    gld_lds16(qkv + (size_t)(b * LSEQ + l0 + r1) * K3 + 2048 + h * 64 + ((scc ^ ((r1 >> 3) & 7)) * 8),
              (char*)T + 4096 + tid * 16);
    __syncthreads();
    #pragma unroll
    for (int it = 0; it < 2; it++) {
      const int cid = tid + it * 256;
      const int dh = cid >> 3, c = (cid & 7) * 8;
      const int sl = (dh >> 3) ^ ((c >> 3) & 7);
      short8 o;
      #pragma unroll
      for (int e = 0; e < 8; e++)
        o[e] = (short)T[(c + e) * 64 + sl * 8 + (dh & 7)];
      *reinterpret_cast<short8*>(vT + ((size_t)bh * DH + dh) * LSEQ + l0 + c) = o;
    }
  }
}

// ---------------------------------------------------------------- MFMA flash attention
// r6 lockstep base (proven best: ~45.6us) with the staging path upgraded:
//  * K staged via global_load_lds (async DMA, no VGPR round-trip; m151: 1.35x
//    vs reg-staging) into LINEAR Ks[64][64]; bank conflicts avoided by
//    XOR-swizzling the GLOBAL SOURCE column (rule #21 pattern: linear dest +
//    inverse-swizzled source + swizzled read — identical scheme to gemm_bt,
//    which measures 0 conflicts).
//  * V is NOT staged: fragments load direct from global, issued right after
//    the wave-span check, consumed only after QK+mask+softmax (~400cy of
//    cover for ~200cy L2 latency). K direct-load was the r3/r8 failure mode
//    (feeds MFMA immediately); V has slack. Removes Vs (LDS 36.9->26.6 KB)
//    and its bank conflicts, and halves the between-barrier staging work.
//  * watermark softmax (r6-proven): m init 9.0; common path has no cross-lane
//    max / no rescale / no p-guards; rare __any(vm>m) path is exact.
__global__ __launch_bounds__(256)
void attn_mfma(const unsigned short* __restrict__ qT, const unsigned short* __restrict__ kT,
               const unsigned short* __restrict__ vT, const int* __restrict__ segs,
               const int* __restrict__ sege, unsigned short* __restrict__ ctx) {
  const int tid  = threadIdx.x;
  const int lane = tid & 63, w = tid >> 6;
  const int quad = lane >> 4, l16 = lane & 15;
  const int qbase = blockIdx.x * 128;
  const int h = blockIdx.y, b = blockIdx.z;
  const size_t bh = (size_t)(b * NH + h);
  const unsigned short* Kg = kT + bh * LSEQ * DH;
  const unsigned short* Vg = vT + bh * DH * LSEQ;

  __shared__ __align__(16) unsigned short Ks[64 * 64];     // linear; swizzled content
  __shared__ __align__(16) unsigned short Ps[4][32 * 72];

  short8 qf[2][2];
  int st[2], en[2];
  #pragma unroll
  for (int g = 0; g < 2; g++) {
    const int qy = qbase + w * 32 + g * 16 + l16;
    const unsigned short* Qrow = qT + (bh * LSEQ + qy) * DH;
    qf[g][0] = *reinterpret_cast<const short8*>(Qrow + quad * 8);
    qf[g][1] = *reinterpret_cast<const short8*>(Qrow + 32 + quad * 8);
    st[g] = segs[b * LSEQ + qy];
    en[g] = sege[b * LSEQ + qy];
  }

  const int kmin = segs[b * LSEQ + qbase] & ~63;
  const int kmax = sege[b * LSEQ + qbase + 127];
  const int wmin = segs[b * LSEQ + qbase + w * 32];
  const int wmax = sege[b * LSEQ + qbase + w * 32 + 31];
  int gmin[2], gmax[2];
  #pragma unroll
  for (int g = 0; g < 2; g++) {
    gmin[g] = segs[b * LSEQ + qbase + w * 32 + g * 16];
    gmax[g] = sege[b * LSEQ + qbase + w * 32 + g * 16 + 15];
  }

  floatx4 acc[2][4];
  #pragma unroll
  for (int g = 0; g < 2; g++)
    #pragma unroll
    for (int dt = 0; dt < 4; dt++) { floatx4 z = {0.f,0.f,0.f,0.f}; acc[g][dt] = z; }
  float m[2] = {9.f, 9.f};          // watermark; rare path handles exceedance
  float lsum[2] = {0.f, 0.f};       // per-lane partials; quad-reduced at end

  // K staging map: thread tid -> row (tid>>3)+32*issue, 16B unit (tid&7).
  // Source column group is XOR-swizzled by (row&7); LDS dest is linear
  // (base + tid*16), as global_load_lds requires.
  const int sr = tid >> 3;          // 0..31
  const int su = tid & 7;
  const int swz0 = (su ^ (sr & 7)) * 8;          // row sr   (issue 0)
  const int swz1 = (su ^ ((sr + 32) & 7)) * 8;   // row sr+32 (issue 1)
  const int xr = l16 & 7;           // read-side swizzle key (row&7 == l16&7)

  for (int kk = kmin; kk < kmax; kk += 64) {
    __syncthreads();
    gld_lds16(Kg + (size_t)(kk + sr) * DH + swz0,      (char*)Ks + tid * 16);
    gld_lds16(Kg + (size_t)(kk + sr + 32) * DH + swz1, (char*)Ks + 4096 + tid * 16);
    __syncthreads();

    if (kk + 64 <= wmin || kk >= wmax) continue;   // tile outside this wave's span

    // V fragments direct from global: issued now, consumed after softmax
    short8 vf[4][2];
    #pragma unroll
    for (int dt = 0; dt < 4; dt++) {
      const unsigned short* vp = Vg + (size_t)(dt * 16 + l16) * LSEQ + kk + quad * 8;
      vf[dt][0] = *reinterpret_cast<const short8*>(vp);
      vf[dt][1] = *reinterpret_cast<const short8*>(vp + 32);
    }

    bool act[2];
    #pragma unroll
    for (int g = 0; g < 2; g++) {
      act[g] = !(kk + 64 <= gmin[g] || kk >= gmax[g]);
      if (!act[g]) continue;

      // S^T = K Q^T; Ks reads use the swizzled column group
      floatx4 sc[4];
      #pragma unroll
      for (int t = 0; t < 4; t++) {
        const int row = t * 16 + l16;
        const short8 kf0 = *reinterpret_cast<const short8*>(Ks + row * 64 + ((quad ^ xr) * 8));
        const short8 kf1 = *reinterpret_cast<const short8*>(Ks + row * 64 + (((quad + 4) ^ xr) * 8));
        floatx4 z = {0.f,0.f,0.f,0.f};
        sc[t] = __builtin_amdgcn_mfma_f32_16x16x32_bf16(kf0, qf[g][0], z, 0, 0, 0);
        sc[t] = __builtin_amdgcn_mfma_f32_16x16x32_bf16(kf1, qf[g][1], sc[t], 0, 0, 0);
      }

      const unsigned span = (unsigned)(en[g] - st[g]);
      float vm = -1e30f;
      #pragma unroll
      for (int t = 0; t < 4; t++) {
        const int k0 = kk + t * 16 + quad * 4;
        #pragma unroll
        for (int r = 0; r < 4; r++) {
          const bool ok = (unsigned)(k0 + r - st[g]) < span;
          sc[t][r] = ok ? sc[t][r] : -1e30f;
          vm = fmaxf(vm, sc[t][r]);
        }
      }

      // rare path: watermark exceeded -> full exact online-softmax rescale
      if (__any(vm > m[g])) {
        float vv = fmaxf(vm, __shfl_xor(vm, 16));
        vv = fmaxf(vv, __shfl_xor(vv, 32));       // wave-uniform new max (> m)
        const float a = __expf(m[g] - vv);
        lsum[g] *= a;
        #pragma unroll
        for (int dt = 0; dt < 4; dt++)
          #pragma unroll
          for (int r = 0; r < 4; r++) acc[g][dt][r] *= a;
        m[g] = vv;
      }

      const float mn = m[g];
      float rs = 0.f;
      #pragma unroll
      for (int t = 0; t < 4; t++) {
        const float p0 = __expf(sc[t][0] - mn);   // exp(-1e30-mn) == 0: masked
        const float p1 = __expf(sc[t][1] - mn);
        const float p2 = __expf(sc[t][2] - mn);
        const float p3 = __expf(sc[t][3] - mn);
        rs += (p0 + p1) + (p2 + p3);
        uint2 pk;
        pk.x = pack_bf16(p0, p1);
        pk.y = pack_bf16(p2, p3);
        *reinterpret_cast<uint2*>(&Ps[w][(g * 16 + l16) * 72 + t * 16 + quad * 4]) = pk;
      }
      lsum[g] += rs;                               // per-lane partial (no shfl)
    }

    // read P for both groups; V fragments (direct) feed both PV updates
    short8 pf[2][2];
    #pragma unroll
    for (int g = 0; g < 2; g++) {
      if (!act[g]) continue;
      pf[g][0] = *reinterpret_cast<const short8*>(&Ps[w][(g * 16 + l16) * 72 + quad * 8]);
      pf[g][1] = *reinterpret_cast<const short8*>(&Ps[w][(g * 16 + l16) * 72 + 32 + quad * 8]);
    }
    #pragma unroll
    for (int dt = 0; dt < 4; dt++) {
      #pragma unroll
      for (int g = 0; g < 2; g++) {
        if (!act[g]) continue;
        // no alpha-rescale here: rare path rescaled acc in place
        acc[g][dt] = __builtin_amdgcn_mfma_f32_16x16x32_bf16(vf[dt][0], pf[g][0], acc[g][dt], 0, 0, 0);
        acc[g][dt] = __builtin_amdgcn_mfma_f32_16x16x32_bf16(vf[dt][1], pf[g][1], acc[g][dt], 0, 0, 0);
      }
    }
  }

  #pragma unroll
  for (int g = 0; g < 2; g++) {
    // deferred cross-quad lsum reduction (once per wave, not per tile)
    lsum[g] += __shfl_xor(lsum[g], 16);
    lsum[g] += __shfl_xor(lsum[g], 32);
    const float inv = (lsum[g] > 0.f) ? 1.f / lsum[g] : 0.f;
    const int qy = qbase + w * 32 + g * 16 + l16;
    unsigned short* orow = ctx + ((size_t)(b * LSEQ + qy)) * D_MODEL + h * DH;
    #pragma unroll
    for (int dt = 0; dt < 4; dt++) {
      uint2 o;
      o.x = pack_bf16(acc[g][dt][0] * inv, acc[g][dt][1] * inv);
      o.y = pack_bf16(acc[g][dt][2] * inv, acc[g][dt][3] * inv);
      *reinterpret_cast<uint2*>(orow + dt * 16 + quad * 4) = o;
    }
  }
}

// ---------------------------------------------------------------- launch
extern "C" void kernel_launch(void* const* d_in, const int* in_sizes, int n_in,
                              void* d_out, int out_size, void* d_ws, size_t ws_size,
                              hipStream_t stream) {
  const float* x      = (const float*)d_in[0];
  const int*   sid    = (const int*)d_in[1];
  const float* ln_w   = (const float*)d_in[2];
  const float* ln_b   = (const float*)d_in[3];
  const float* w_qkv  = (const float*)d_in[4];
  const float* q_ln_w = (const float*)d_in[5];
  const float* k_ln_w = (const float*)d_in[6];
  const float* w_out  = (const float*)d_in[7];
  float* out = (float*)d_out;
  char* ws = (char*)d_ws;

  constexpr size_t OFF_WQKVT = 0;                        //  6,291,456
  constexpr size_t OFF_WOUTT = 6291456;                  //  2,097,152
  constexpr size_t OFF_H     = 8388608;                  // 16,777,216
  constexpr size_t OFF_QKV   = 25165824;                 // 50,331,648 (bf16)
  constexpr size_t OFF_QT    = 75497472;                 // 16,777,216
  constexpr size_t OFF_KT    = 92274688;                 // 16,777,216
  constexpr size_t OFF_VT    = 109051904;                // 16,777,216
  constexpr size_t OFF_CTX   = 125829120;                // 16,777,216
  constexpr size_t OFF_SEGS  = 142606336;                // 32,768
  constexpr size_t OFF_SEGE  = 142639104;                // 32,768

  __hip_bfloat16* wqkvT = (__hip_bfloat16*)(ws + OFF_WQKVT);
  __hip_bfloat16* woutT = (__hip_bfloat16*)(ws + OFF_WOUTT);
  __hip_bfloat16* hbuf  = (__hip_bfloat16*)(ws + OFF_H);
  __hip_bfloat16* qkvb  = (__hip_bfloat16*)(ws + OFF_QKV);
  unsigned short* qTb   = (unsigned short*)(ws + OFF_QT);
  unsigned short* kTb   = (unsigned short*)(ws + OFF_KT);
  unsigned short* vTb   = (unsigned short*)(ws + OFF_VT);
  unsigned short* ctx   = (unsigned short*)(ws + OFF_CTX);
  int*            segst = (int*)(ws + OFF_SEGS);
  int*            segen = (int*)(ws + OFF_SEGE);

  prep_kernel<<<6176, 256, 0, stream>>>(x, ln_w, ln_b, w_qkv, w_out, sid,
                                        hbuf, wqkvT, woutT, segst, segen);
  gemm_bt<__hip_bfloat16><<<dim3(K3 / 128, NTOK / 128), 256, 0, stream>>>(
      hbuf, wqkvT, qkvb, NTOK, K3, 1024);
  ropevt_kernel<<<4096, 256, 0, stream>>>((const unsigned short*)qkvb, q_ln_w, k_ln_w,
                                          qTb, kTb, vTb);
  attn_mfma<<<dim3(LSEQ / 128, NH, BATCH), 256, 0, stream>>>(qTb, kTb, vTb, segst, segen, ctx);
  gemm_bt<float><<<dim3(D_MODEL / 128, NTOK / 128), 256, 0, stream>>>(
      (const __hip_bfloat16*)ctx, woutT, out, NTOK, D_MODEL, 1024);
}

// Round 10
// 242.726 us; speedup vs baseline: 1.1065x; 1.0334x over previous
//
#include <hip/hip_runtime.h>
#include <hip/hip_bf16.h>
#include <cstdint>
#include <cstddef>
#include <type_traits>

#define D_MODEL 1024
#define NH      16
#define DH      64
#define LSEQ    2048
#define BATCH   4
#define NTOK    8192      // BATCH * LSEQ
#define K3      3072

typedef __attribute__((ext_vector_type(8))) short  short8;
typedef __attribute__((ext_vector_type(4))) float  floatx4;

__device__ __forceinline__ unsigned short f2bf_bits(float f) {
  __hip_bfloat16 h = __float2bfloat16(f);
  return __builtin_bit_cast(unsigned short, h);
}
__device__ __forceinline__ float bf2f(unsigned short u) {
  return __bfloat162float(__builtin_bit_cast(__hip_bfloat16, u));
}
__device__ __forceinline__ unsigned int pack_bf16(float lo, float hi) {
  return (unsigned int)f2bf_bits(lo) | ((unsigned int)f2bf_bits(hi) << 16);
}

__device__ __forceinline__ void gld_lds16(const void* g, void* l) {
  __builtin_amdgcn_global_load_lds(
      (const __attribute__((address_space(1))) void*)g,
      (__attribute__((address_space(3))) void*)l,
      16, 0, 0);
}

// ---------------------------------------------------------------- fused prologue
// blocks [0,3072): transpose+cast w_qkv [1024][3072] -> wqkvT [3072][1024]
// blocks [3072,4096): transpose+cast w_out [1024][1024] -> woutT
// blocks [4096,6144): LayerNorm(x) -> hbuf (4 tokens/block, wave per token)
// blocks [6144,6176): segment bounds
__global__ __launch_bounds__(256)
void prep_kernel(const float* __restrict__ x, const float* __restrict__ ln_w,
                 const float* __restrict__ ln_b, const float* __restrict__ w_qkv,
                 const float* __restrict__ w_out, const int* __restrict__ sid,
                 __hip_bfloat16* __restrict__ hbuf, __hip_bfloat16* __restrict__ wqkvT,
                 __hip_bfloat16* __restrict__ woutT, int* __restrict__ segstart,
                 int* __restrict__ segend) {
  __shared__ __align__(16) char smem[8448];
  const int blk = blockIdx.x;
  const int tid = threadIdx.x;

  if (blk < 4096) {
    float (*tile)[33] = reinterpret_cast<float(*)[33]>(smem);
    const float* src;  __hip_bfloat16* dst;  int R, C, bx, by;
    if (blk < 3072) { src = w_qkv; dst = wqkvT; R = 1024; C = 3072; bx = blk % 96; by = blk / 96; }
    else            { src = w_out; dst = woutT; R = 1024; C = 1024; bx = (blk - 3072) & 31; by = (blk - 3072) >> 5; }
    const int c0 = bx * 32, r0 = by * 32;
    const int xx = tid & 31, yy = tid >> 5;   // 32 x 8
    #pragma unroll
    for (int j = 0; j < 32; j += 8)
      tile[yy + j][xx] = src[(size_t)(r0 + yy + j) * C + c0 + xx];
    __syncthreads();
    #pragma unroll
    for (int j = 0; j < 32; j += 8)
      dst[(size_t)(c0 + yy + j) * R + r0 + xx] = __float2bfloat16(tile[xx][yy + j]);
  } else if (blk < 6144) {
    const int lane = tid & 63;
    const int t = (blk - 4096) * 4 + (tid >> 6);
    const float4* xr = reinterpret_cast<const float4*>(x) + (size_t)t * 256;
    float4 v[4];
    float s = 0.f, ss = 0.f;
    #pragma unroll
    for (int i = 0; i < 4; i++) {
      v[i] = xr[lane + i * 64];
      s  += (v[i].x + v[i].y) + (v[i].z + v[i].w);
      ss += (v[i].x*v[i].x + v[i].y*v[i].y) + (v[i].z*v[i].z + v[i].w*v[i].w);
    }
    #pragma unroll
    for (int off = 1; off < 64; off <<= 1) {
      s  += __shfl_xor(s, off);
      ss += __shfl_xor(ss, off);
    }
    const float mu = s * (1.f / 1024);
    const float rs = rsqrtf(ss * (1.f / 1024) - mu * mu + 1e-5f);
    const float4* wr = reinterpret_cast<const float4*>(ln_w);
    const float4* br = reinterpret_cast<const float4*>(ln_b);
    ushort4* hr = reinterpret_cast<ushort4*>(hbuf) + (size_t)t * 256;
    #pragma unroll
    for (int i = 0; i < 4; i++) {
      const float4 wv = wr[lane + i * 64];
      const float4 bv = br[lane + i * 64];
      ushort4 o;
      o.x = f2bf_bits((v[i].x - mu) * rs * wv.x + bv.x);
      o.y = f2bf_bits((v[i].y - mu) * rs * wv.y + bv.y);
      o.z = f2bf_bits((v[i].z - mu) * rs * wv.z + bv.z);
      o.w = f2bf_bits((v[i].w - mu) * rs * wv.w + bv.w);
      hr[lane + i * 64] = o;
    }
  } else {
    int* srow = reinterpret_cast<int*>(smem);
    const int sblk = blk - 6144;            // 0..31, 8 per batch
    const int b = sblk >> 3;
    const int* row = sid + (size_t)b * LSEQ;
    #pragma unroll
    for (int i = 0; i < 8; i++) srow[tid + i * 256] = row[tid + i * 256];
    __syncthreads();
    const int l = (sblk & 7) * 256 + tid;
    const int v = srow[l];
    int lo = 0, hi = l;
    while (lo < hi) { int mid = (lo + hi) >> 1; if (srow[mid] < v) lo = mid + 1; else hi = mid; }
    const int i = b * LSEQ + l;
    segstart[i] = lo;
    lo = l + 1; hi = LSEQ;
    while (lo < hi) { int mid = (lo + hi) >> 1; if (srow[mid] <= v) lo = mid + 1; else hi = mid; }
    segend[i] = lo;
  }
}

// ---------------------------------------------------------------- bf16 GEMM, Bt layout
// BK=64, XOR-swizzled LDS (conflict-free). launch_bounds(256,2): measured best.
// VSPLIT (gemm1 only): blocks with bn>=2048 compute the V third of qkv and
// write it DIRECTLY in vT's [b,h,dh,l] transposed layout (per lane: 4
// consecutive l at fixed dh = one packed 8B store), skipping the qkvb write.
// This deletes ropevt's entire vtrans pass (V needs no LN/rope — the old
// qkvb->vT round-trip was a pure layout change costing ~34MB of traffic).
template <typename OutT, bool VSPLIT>
__global__ __launch_bounds__(256, 2)
void gemm_bt(const __hip_bfloat16* __restrict__ A, const __hip_bfloat16* __restrict__ Bt,
             OutT* __restrict__ C, unsigned short* __restrict__ vT,
             int M, int N, int K) {
  const int tid  = threadIdx.x;
  const int lane = tid & 63;
  const int wave = tid >> 6;
  const int bm = blockIdx.y * 128;
  const int bn = blockIdx.x * 128;
  const int wm = (wave & 1) * 64;
  const int wn = (wave >> 1) * 64;
  const int quad = lane >> 4;
  const int l16  = lane & 15;

  __shared__ __align__(16) __hip_bfloat16 As[128 * 64];
  __shared__ __align__(16) __hip_bfloat16 Bs[128 * 64];

  floatx4 acc[4][4];
  #pragma unroll
  for (int i = 0; i < 4; i++)
    #pragma unroll
    for (int j = 0; j < 4; j++) {
      floatx4 z = {0.f, 0.f, 0.f, 0.f};
      acc[i][j] = z;
    }

  const int srow = tid >> 3;
  const int sq   = tid & 7;
  const int sc8  = (sq ^ (srow & 7)) * 8;
  const __hip_bfloat16* Ab = A  + (size_t)(bm + srow) * K + sc8;
  const __hip_bfloat16* Bb = Bt + (size_t)(bn + srow) * K + sc8;

  const int axr = l16 & 7;

  for (int k0 = 0; k0 < K; k0 += 64) {
    __syncthreads();
    #pragma unroll
    for (int p = 0; p < 4; p++) {
      gld_lds16(Ab + (size_t)(p * 32) * K + k0, (char*)As + p * 4096 + tid * 16);
      gld_lds16(Bb + (size_t)(p * 32) * K + k0, (char*)Bs + p * 4096 + tid * 16);
    }
    __syncthreads();
    #pragma unroll
    for (int s0 = 0; s0 < 2; s0++) {
      const int qo = ((s0 * 4 + quad) ^ axr) * 8;
      short8 af[4], bfr[4];
      #pragma unroll
      for (int i = 0; i < 4; i++)
        af[i] = *reinterpret_cast<const short8*>(As + (wm + i * 16 + l16) * 64 + qo);
      #pragma unroll
      for (int j = 0; j < 4; j++)
        bfr[j] = *reinterpret_cast<const short8*>(Bs + (wn + j * 16 + l16) * 64 + qo);
      #pragma unroll
      for (int i = 0; i < 4; i++)
        #pragma unroll
        for (int j = 0; j < 4; j++)
          acc[i][j] = __builtin_amdgcn_mfma_f32_16x16x32_bf16(af[i], bfr[j], acc[i][j], 0, 0, 0);
    }
  }

  if constexpr (VSPLIT) {
    if (bn >= 2048) {
      // V third: write straight into vT[((b*16+h)*64+dh)*2048 + l]
      const int b  = bm >> 11;                  // token row -> batch
      const int l0 = (bm & 2047) + wm;          // token-in-sequence base
      const int hh = ((bn - 2048) >> 6) + (wn >> 6);   // head (uniform per wave)
      #pragma unroll
      for (int i = 0; i < 4; i++) {
        const int l = l0 + i * 16 + quad * 4;   // 4 consecutive l per lane (r=0..3)
        #pragma unroll
        for (int j = 0; j < 4; j++) {
          const int dh = j * 16 + l16;
          uint2 o;
          o.x = pack_bf16(acc[i][j][0], acc[i][j][1]);
          o.y = pack_bf16(acc[i][j][2], acc[i][j][3]);
          *reinterpret_cast<uint2*>(vT + ((size_t)(b * NH + hh) * DH + dh) * LSEQ + l) = o;
        }
      }
      return;
    }
  }

  #pragma unroll
  for (int i = 0; i < 4; i++)
    #pragma unroll
    for (int j = 0; j < 4; j++) {
      const int row0 = bm + wm + i * 16 + quad * 4;
      const int col  = bn + wn + j * 16 + l16;
      #pragma unroll
      for (int r = 0; r < 4; r++) {
        if constexpr (std::is_same<OutT, __hip_bfloat16>::value)
          C[(size_t)(row0 + r) * N + col] = __float2bfloat16(acc[i][j][r]);
        else
          C[(size_t)(row0 + r) * N + col] = acc[i][j][r];
      }
    }
}

// ---------------------------------------------------------------- fused rope (Q/K only)
// V is written transposed by gemm1's epilogue (VSPLIT) — the old vtrans blocks
// (2048..4095) are gone; grid is now 2048 blocks.
__global__ __launch_bounds__(256)
void ropevt_kernel(const unsigned short* __restrict__ qkv, const float* __restrict__ qw,
                   const float* __restrict__ kw, unsigned short* __restrict__ qT,
                   unsigned short* __restrict__ kT) {
  const int blk = blockIdx.x;
  const int tid = threadIdx.x;

  const int lane = tid & 63;
  const int t = blk * 4 + (tid >> 6);
  const int b = t >> 11, l = t & 2047;
  const unsigned short* row = qkv + (size_t)t * K3;
  const int hh = lane >> 2;
  const int jb = (lane & 3) * 8;
  const int base = hh * 64 + jb;

  const short8 qa_u = *reinterpret_cast<const short8*>(row + base);
  const short8 qb_u = *reinterpret_cast<const short8*>(row + base + 32);
  const short8 ka_u = *reinterpret_cast<const short8*>(row + 1024 + base);
  const short8 kb_u = *reinterpret_cast<const short8*>(row + 1024 + base + 32);

  float qa[8], qb[8], ka[8], kb[8];
  float s_q = 0.f, ss_q = 0.f, s_k = 0.f, ss_k = 0.f;
  #pragma unroll
  for (int e = 0; e < 8; e++) {
    qa[e] = bf2f((unsigned short)qa_u[e]); qb[e] = bf2f((unsigned short)qb_u[e]);
    ka[e] = bf2f((unsigned short)ka_u[e]); kb[e] = bf2f((unsigned short)kb_u[e]);
    s_q  += qa[e] + qb[e];  ss_q += qa[e]*qa[e] + qb[e]*qb[e];
    s_k  += ka[e] + kb[e];  ss_k += ka[e]*ka[e] + kb[e]*kb[e];
  }
  #pragma unroll
  for (int off = 1; off < 64; off <<= 1) {
    s_q  += __shfl_xor(s_q, off);  ss_q += __shfl_xor(ss_q, off);
    s_k  += __shfl_xor(s_k, off);  ss_k += __shfl_xor(ss_k, off);
  }
  const float qmu = s_q * (1.f/1024);
  const float qrs = rsqrtf(ss_q * (1.f/1024) - qmu*qmu + 1e-5f);
  const float kmu = s_k * (1.f/1024);
  const float krs = rsqrtf(ss_k * (1.f/1024) - kmu*kmu + 1e-5f);

  const int j0 = lane & 31;
  const float invf = __expf(-(float)j0 * 0.28782313662425575f);   // ln(1e4)/32
  float tsin, tcos;
  sincosf((float)l * invf, &tsin, &tcos);

  const float4 wq0 = *reinterpret_cast<const float4*>(qw + base);
  const float4 wq1 = *reinterpret_cast<const float4*>(qw + base + 4);
  const float4 wq2 = *reinterpret_cast<const float4*>(qw + base + 32);
  const float4 wq3 = *reinterpret_cast<const float4*>(qw + base + 36);
  const float4 wk0 = *reinterpret_cast<const float4*>(kw + base);
  const float4 wk1 = *reinterpret_cast<const float4*>(kw + base + 4);
  const float4 wk2 = *reinterpret_cast<const float4*>(kw + base + 32);
  const float4 wk3 = *reinterpret_cast<const float4*>(kw + base + 36);
  const float wqa[8] = {wq0.x,wq0.y,wq0.z,wq0.w, wq1.x,wq1.y,wq1.z,wq1.w};
  const float wqb[8] = {wq2.x,wq2.y,wq2.z,wq2.w, wq3.x,wq3.y,wq3.z,wq3.w};
  const float wka[8] = {wk0.x,wk0.y,wk0.z,wk0.w, wk1.x,wk1.y,wk1.z,wk1.w};
  const float wkb[8] = {wk2.x,wk2.y,wk2.z,wk2.w, wk3.x,wk3.y,wk3.z,wk3.w};

  short8 oqa, oqb, oka, okb;
  #pragma unroll
  for (int e = 0; e < 8; e++) {
    const int j = jb + e;
    const float c  = __shfl(tcos, j);
    const float sn = __shfl(tsin, j);
    const float qn1 = (qa[e] - qmu) * qrs * wqa[e];
    const float qn2 = (qb[e] - qmu) * qrs * wqb[e];
    const float kn1 = (ka[e] - kmu) * krs * wka[e];
    const float kn2 = (kb[e] - kmu) * krs * wkb[e];
    oqa[e] = (short)f2bf_bits((qn1 * c - qn2 * sn) * 0.125f);
    oqb[e] = (short)f2bf_bits((qn2 * c + qn1 * sn) * 0.125f);
    oka[e] = (short)f2bf_bits(kn1 * c - kn2 * sn);
    okb[e] = (short)f2bf_bits(kn2 * c + kn1 * sn);
  }
  const size_t ob = ((size_t)(b * NH + hh) * LSEQ + l) * DH + jb;
  *reinterpret_cast<short8*>(qT + ob)      = oqa;
  *reinterpret_cast<short8*>(qT + ob + 32) = oqb;
  *reinterpret_cast<short8*>(kT + ob)      = oka;
  *reinterpret_cast<short8*>(kT + ob + 32) = okb;
}

// ---------------------------------------------------------------- MFMA flash attention
// r6 (best-measured) verbatim: LDS-staged K/V lockstep, stride-72 padded LDS,
// watermark softmax (m=9 init; common path has no cross-lane max / no rescale /
// no p-guards; rare __any(vm>m) path is exact online-softmax).
__global__ __launch_bounds__(256)
void attn_mfma(const unsigned short* __restrict__ qT, const unsigned short* __restrict__ kT,
               const unsigned short* __restrict__ vT, const int* __restrict__ segs,
               const int* __restrict__ sege, unsigned short* __restrict__ ctx) {
  const int tid  = threadIdx.x;
  const int lane = tid & 63, w = tid >> 6;
  const int quad = lane >> 4, l16 = lane & 15;
  const int qbase = blockIdx.x * 128;
  const int h = blockIdx.y, b = blockIdx.z;
  const size_t bh = (size_t)(b * NH + h);
  const unsigned short* Kg = kT + bh * LSEQ * DH;
  const unsigned short* Vg = vT + bh * DH * LSEQ;

  __shared__ __align__(16) unsigned short Ks[64 * 72];
  __shared__ __align__(16) unsigned short Vs[64 * 72];
  __shared__ __align__(16) unsigned short Ps[4][32 * 72];

  short8 qf[2][2];
  int st[2], en[2];
  #pragma unroll
  for (int g = 0; g < 2; g++) {
    const int qy = qbase + w * 32 + g * 16 + l16;
    const unsigned short* Qrow = qT + (bh * LSEQ + qy) * DH;
    qf[g][0] = *reinterpret_cast<const short8*>(Qrow + quad * 8);
    qf[g][1] = *reinterpret_cast<const short8*>(Qrow + 32 + quad * 8);
    st[g] = segs[b * LSEQ + qy];
    en[g] = sege[b * LSEQ + qy];
  }

  const int kmin = segs[b * LSEQ + qbase] & ~63;
  const int kmax = sege[b * LSEQ + qbase + 127];
  const int wmin = segs[b * LSEQ + qbase + w * 32];
  const int wmax = sege[b * LSEQ + qbase + w * 32 + 31];
  int gmin[2], gmax[2];
  #pragma unroll
  for (int g = 0; g < 2; g++) {
    gmin[g] = segs[b * LSEQ + qbase + w * 32 + g * 16];
    gmax[g] = sege[b * LSEQ + qbase + w * 32 + g * 16 + 15];
  }

  floatx4 acc[2][4];
  #pragma unroll
  for (int g = 0; g < 2; g++)
    #pragma unroll
    for (int dt = 0; dt < 4; dt++) { floatx4 z = {0.f,0.f,0.f,0.f}; acc[g][dt] = z; }
  float m[2] = {9.f, 9.f};          // watermark; rare path handles exceedance
  float lsum[2] = {0.f, 0.f};       // per-lane partials; quad-reduced at end

  const int r_ = tid >> 3, c_ = (tid & 7) * 8;

  for (int kk = kmin; kk < kmax; kk += 64) {
    __syncthreads();
    #pragma unroll
    for (int it = 0; it < 2; it++) {
      const int r = r_ + it * 32;
      *reinterpret_cast<short8*>(Ks + r * 72 + c_) =
          *reinterpret_cast<const short8*>(Kg + (size_t)(kk + r) * DH + c_);
      *reinterpret_cast<short8*>(Vs + r * 72 + c_) =
          *reinterpret_cast<const short8*>(Vg + (size_t)r * LSEQ + kk + c_);
    }
    __syncthreads();

    if (kk + 64 <= wmin || kk >= wmax) continue;   // tile outside this wave's 32-query span

    bool act[2];
    #pragma unroll
    for (int g = 0; g < 2; g++) {
      act[g] = !(kk + 64 <= gmin[g] || kk >= gmax[g]);
      if (!act[g]) continue;

      // S^T = K Q^T for this group's 16 queries
      floatx4 sc[4];
      #pragma unroll
      for (int t = 0; t < 4; t++) {
        const short8 kf0 = *reinterpret_cast<const short8*>(Ks + (t * 16 + l16) * 72 + quad * 8);
        const short8 kf1 = *reinterpret_cast<const short8*>(Ks + (t * 16 + l16) * 72 + 32 + quad * 8);
        floatx4 z = {0.f,0.f,0.f,0.f};
        sc[t] = __builtin_amdgcn_mfma_f32_16x16x32_bf16(kf0, qf[g][0], z, 0, 0, 0);
        sc[t] = __builtin_amdgcn_mfma_f32_16x16x32_bf16(kf1, qf[g][1], sc[t], 0, 0, 0);
      }

      const unsigned span = (unsigned)(en[g] - st[g]);
      float vm = -1e30f;
      #pragma unroll
      for (int t = 0; t < 4; t++) {
        const int k0 = kk + t * 16 + quad * 4;
        #pragma unroll
        for (int r = 0; r < 4; r++) {
          const bool ok = (unsigned)(k0 + r - st[g]) < span;
          sc[t][r] = ok ? sc[t][r] : -1e30f;
          vm = fmaxf(vm, sc[t][r]);
        }
      }

      // rare path: watermark exceeded -> full exact online-softmax rescale
      if (__any(vm > m[g])) {
        float vv = fmaxf(vm, __shfl_xor(vm, 16));
        vv = fmaxf(vv, __shfl_xor(vv, 32));       // wave-uniform new max (> m)
        const float a = __expf(m[g] - vv);
        lsum[g] *= a;
        #pragma unroll
        for (int dt = 0; dt < 4; dt++)
          #pragma unroll
          for (int r = 0; r < 4; r++) acc[g][dt][r] *= a;
        m[g] = vv;
      }

      const float mn = m[g];
      float rs = 0.f;
      #pragma unroll
      for (int t = 0; t < 4; t++) {
        const float p0 = __expf(sc[t][0] - mn);   // exp(-1e30-mn) == 0: masked
        const float p1 = __expf(sc[t][1] - mn);
        const float p2 = __expf(sc[t][2] - mn);
        const float p3 = __expf(sc[t][3] - mn);
        rs += (p0 + p1) + (p2 + p3);
        uint2 pk;
        pk.x = pack_bf16(p0, p1);
        pk.y = pack_bf16(p2, p3);
        *reinterpret_cast<uint2*>(&Ps[w][(g * 16 + l16) * 72 + t * 16 + quad * 4]) = pk;
      }
      lsum[g] += rs;                               // per-lane partial (no shfl)
    }

    // read P for both groups, then shared V fragments feed both PV updates
    short8 pf[2][2];
    #pragma unroll
    for (int g = 0; g < 2; g++) {
      if (!act[g]) continue;
      pf[g][0] = *reinterpret_cast<const short8*>(&Ps[w][(g * 16 + l16) * 72 + quad * 8]);
      pf[g][1] = *reinterpret_cast<const short8*>(&Ps[w][(g * 16 + l16) * 72 + 32 + quad * 8]);
    }
    #pragma unroll
    for (int dt = 0; dt < 4; dt++) {
      const short8 vf0 = *reinterpret_cast<const short8*>(Vs + (dt * 16 + l16) * 72 + quad * 8);
      const short8 vf1 = *reinterpret_cast<const short8*>(Vs + (dt * 16 + l16) * 72 + 32 + quad * 8);
      #pragma unroll
      for (int g = 0; g < 2; g++) {
        if (!act[g]) continue;
        // no alpha-rescale here: rare path rescaled acc in place
        acc[g][dt] = __builtin_amdgcn_mfma_f32_16x16x32_bf16(vf0, pf[g][0], acc[g][dt], 0, 0, 0);
        acc[g][dt] = __builtin_amdgcn_mfma_f32_16x16x32_bf16(vf1, pf[g][1], acc[g][dt], 0, 0, 0);
      }
    }
  }

  #pragma unroll
  for (int g = 0; g < 2; g++) {
    // deferred cross-quad lsum reduction (once per wave, not per tile)
    lsum[g] += __shfl_xor(lsum[g], 16);
    lsum[g] += __shfl_xor(lsum[g], 32);
    const float inv = (lsum[g] > 0.f) ? 1.f / lsum[g] : 0.f;
    const int qy = qbase + w * 32 + g * 16 + l16;
    unsigned short* orow = ctx + ((size_t)(b * LSEQ + qy)) * D_MODEL + h * DH;
    #pragma unroll
    for (int dt = 0; dt < 4; dt++) {
      uint2 o;
      o.x = pack_bf16(acc[g][dt][0] * inv, acc[g][dt][1] * inv);
      o.y = pack_bf16(acc[g][dt][2] * inv, acc[g][dt][3] * inv);
      *reinterpret_cast<uint2*>(orow + dt * 16 + quad * 4) = o;
    }
  }
}

// ---------------------------------------------------------------- launch
extern "C" void kernel_launch(void* const* d_in, const int* in_sizes, int n_in,
                              void* d_out, int out_size, void* d_ws, size_t ws_size,
                              hipStream_t stream) {
  const float* x      = (const float*)d_in[0];
  const int*   sid    = (const int*)d_in[1];
  const float* ln_w   = (const float*)d_in[2];
  const float* ln_b   = (const float*)d_in[3];
  const float* w_qkv  = (const float*)d_in[4];
  const float* q_ln_w = (const float*)d_in[5];
  const float* k_ln_w = (const float*)d_in[6];
  const float* w_out  = (const float*)d_in[7];
  float* out = (float*)d_out;
  char* ws = (char*)d_ws;

  constexpr size_t OFF_WQKVT = 0;                        //  6,291,456
  constexpr size_t OFF_WOUTT = 6291456;                  //  2,097,152
  constexpr size_t OFF_H     = 8388608;                  // 16,777,216
  constexpr size_t OFF_QKV   = 25165824;                 // 50,331,648 (bf16)
  constexpr size_t OFF_QT    = 75497472;                 // 16,777,216
  constexpr size_t OFF_KT    = 92274688;                 // 16,777,216
  constexpr size_t OFF_VT    = 109051904;                // 16,777,216
  constexpr size_t OFF_CTX   = 125829120;                // 16,777,216
  constexpr size_t OFF_SEGS  = 142606336;                // 32,768
  constexpr size_t OFF_SEGE  = 142639104;                // 32,768

  __hip_bfloat16* wqkvT = (__hip_bfloat16*)(ws + OFF_WQKVT);
  __hip_bfloat16* woutT = (__hip_bfloat16*)(ws + OFF_WOUTT);
  __hip_bfloat16* hbuf  = (__hip_bfloat16*)(ws + OFF_H);
  __hip_bfloat16* qkvb  = (__hip_bfloat16*)(ws + OFF_QKV);
  unsigned short* qTb   = (unsigned short*)(ws + OFF_QT);
  unsigned short* kTb   = (unsigned short*)(ws + OFF_KT);
  unsigned short* vTb   = (unsigned short*)(ws + OFF_VT);
  unsigned short* ctx   = (unsigned short*)(ws + OFF_CTX);
  int*            segst = (int*)(ws + OFF_SEGS);
  int*            segen = (int*)(ws + OFF_SEGE);

  prep_kernel<<<6176, 256, 0, stream>>>(x, ln_w, ln_b, w_qkv, w_out, sid,
                                        hbuf, wqkvT, woutT, segst, segen);
  gemm_bt<__hip_bfloat16, true><<<dim3(K3 / 128, NTOK / 128), 256, 0, stream>>>(
      hbuf, wqkvT, qkvb, vTb, NTOK, K3, 1024);
  ropevt_kernel<<<2048, 256, 0, stream>>>((const unsigned short*)qkvb, q_ln_w, k_ln_w,
                                          qTb, kTb);
  attn_mfma<<<dim3(LSEQ / 128, NH, BATCH), 256, 0, stream>>>(qTb, kTb, vTb, segst, segen, ctx);
  gemm_bt<float, false><<<dim3(D_MODEL / 128, NTOK / 128), 256, 0, stream>>>(
      (const __hip_bfloat16*)ctx, woutT, out, nullptr, NTOK, D_MODEL, 1024);
}

// Round 11
// 231.411 us; speedup vs baseline: 1.1606x; 1.0489x over previous
//
#include <hip/hip_runtime.h>
#include <hip/hip_bf16.h>
#include <cstdint>
#include <cstddef>
#include <type_traits>

#define D_MODEL 1024
#define NH      16
#define DH      64
#define LSEQ    2048
#define BATCH   4
#define NTOK    8192      // BATCH * LSEQ
#define K3      3072

typedef __attribute__((ext_vector_type(8))) short  short8;
typedef __attribute__((ext_vector_type(4))) float  floatx4;

__device__ __forceinline__ unsigned short f2bf_bits(float f) {
  __hip_bfloat16 h = __float2bfloat16(f);
  return __builtin_bit_cast(unsigned short, h);
}
__device__ __forceinline__ float bf2f(unsigned short u) {
  return __bfloat162float(__builtin_bit_cast(__hip_bfloat16, u));
}
__device__ __forceinline__ unsigned int pack_bf16(float lo, float hi) {
  return (unsigned int)f2bf_bits(lo) | ((unsigned int)f2bf_bits(hi) << 16);
}

__device__ __forceinline__ void gld_lds16(const void* g, void* l) {
  __builtin_amdgcn_global_load_lds(
      (const __attribute__((address_space(1))) void*)g,
      (__attribute__((address_space(3))) void*)l,
      16, 0, 0);
}

// ---------------------------------------------------------------- fused prologue
// blocks [0,3072): transpose+cast w_qkv [1024][3072] -> wqkvT [3072][1024]
// blocks [3072,4096): transpose+cast w_out [1024][1024] -> woutT
// blocks [4096,6144): LayerNorm(x) -> hbuf (4 tokens/block, wave per token)
// blocks [6144,6176): segment bounds
__global__ __launch_bounds__(256)
void prep_kernel(const float* __restrict__ x, const float* __restrict__ ln_w,
                 const float* __restrict__ ln_b, const float* __restrict__ w_qkv,
                 const float* __restrict__ w_out, const int* __restrict__ sid,
                 __hip_bfloat16* __restrict__ hbuf, __hip_bfloat16* __restrict__ wqkvT,
                 __hip_bfloat16* __restrict__ woutT, int* __restrict__ segstart,
                 int* __restrict__ segend) {
  __shared__ __align__(16) char smem[8448];
  const int blk = blockIdx.x;
  const int tid = threadIdx.x;

  if (blk < 4096) {
    float (*tile)[33] = reinterpret_cast<float(*)[33]>(smem);
    const float* src;  __hip_bfloat16* dst;  int R, C, bx, by;
    if (blk < 3072) { src = w_qkv; dst = wqkvT; R = 1024; C = 3072; bx = blk % 96; by = blk / 96; }
    else            { src = w_out; dst = woutT; R = 1024; C = 1024; bx = (blk - 3072) & 31; by = (blk - 3072) >> 5; }
    const int c0 = bx * 32, r0 = by * 32;
    const int xx = tid & 31, yy = tid >> 5;   // 32 x 8
    #pragma unroll
    for (int j = 0; j < 32; j += 8)
      tile[yy + j][xx] = src[(size_t)(r0 + yy + j) * C + c0 + xx];
    __syncthreads();
    #pragma unroll
    for (int j = 0; j < 32; j += 8)
      dst[(size_t)(c0 + yy + j) * R + r0 + xx] = __float2bfloat16(tile[xx][yy + j]);
  } else if (blk < 6144) {
    const int lane = tid & 63;
    const int t = (blk - 4096) * 4 + (tid >> 6);
    const float4* xr = reinterpret_cast<const float4*>(x) + (size_t)t * 256;
    float4 v[4];
    float s = 0.f, ss = 0.f;
    #pragma unroll
    for (int i = 0; i < 4; i++) {
      v[i] = xr[lane + i * 64];
      s  += (v[i].x + v[i].y) + (v[i].z + v[i].w);
      ss += (v[i].x*v[i].x + v[i].y*v[i].y) + (v[i].z*v[i].z + v[i].w*v[i].w);
    }
    #pragma unroll
    for (int off = 1; off < 64; off <<= 1) {
      s  += __shfl_xor(s, off);
      ss += __shfl_xor(ss, off);
    }
    const float mu = s * (1.f / 1024);
    const float rs = rsqrtf(ss * (1.f / 1024) - mu * mu + 1e-5f);
    const float4* wr = reinterpret_cast<const float4*>(ln_w);
    const float4* br = reinterpret_cast<const float4*>(ln_b);
    ushort4* hr = reinterpret_cast<ushort4*>(hbuf) + (size_t)t * 256;
    #pragma unroll
    for (int i = 0; i < 4; i++) {
      const float4 wv = wr[lane + i * 64];
      const float4 bv = br[lane + i * 64];
      ushort4 o;
      o.x = f2bf_bits((v[i].x - mu) * rs * wv.x + bv.x);
      o.y = f2bf_bits((v[i].y - mu) * rs * wv.y + bv.y);
      o.z = f2bf_bits((v[i].z - mu) * rs * wv.z + bv.z);
      o.w = f2bf_bits((v[i].w - mu) * rs * wv.w + bv.w);
      hr[lane + i * 64] = o;
    }
  } else {
    int* srow = reinterpret_cast<int*>(smem);
    const int sblk = blk - 6144;            // 0..31, 8 per batch
    const int b = sblk >> 3;
    const int* row = sid + (size_t)b * LSEQ;
    #pragma unroll
    for (int i = 0; i < 8; i++) srow[tid + i * 256] = row[tid + i * 256];
    __syncthreads();
    const int l = (sblk & 7) * 256 + tid;
    const int v = srow[l];
    int lo = 0, hi = l;
    while (lo < hi) { int mid = (lo + hi) >> 1; if (srow[mid] < v) lo = mid + 1; else hi = mid; }
    const int i = b * LSEQ + l;
    segstart[i] = lo;
    lo = l + 1; hi = LSEQ;
    while (lo < hi) { int mid = (lo + hi) >> 1; if (srow[mid] <= v) lo = mid + 1; else hi = mid; }
    segend[i] = lo;
  }
}

// ---------------------------------------------------------------- bf16 GEMM, Bt layout
// BK=64, XOR-swizzled LDS (conflict-free). launch_bounds(256,2): measured best.
// VSPLIT (gemm1 only): blocks with bn>=2048 compute the V third of qkv and
// write it DIRECTLY in vT's [b,h,dh,l] transposed layout, bounced through an
// LDS tile T[128 cols][136] so the global stores are 256B-coalesced segments
// (r10's direct 8B-scattered stores cost GEMM1 ~5us: MfmaUtil 39->34).
// Pad 136: 272B row stride keeps 16B alignment; write/read phases land at the
// LDS inherent-BW floor (no excess bank conflict). Deletes ropevt's vtrans.
template <typename OutT, bool VSPLIT>
__global__ __launch_bounds__(256, 2)
void gemm_bt(const __hip_bfloat16* __restrict__ A, const __hip_bfloat16* __restrict__ Bt,
             OutT* __restrict__ C, unsigned short* __restrict__ vT,
             int M, int N, int K) {
  const int tid  = threadIdx.x;
  const int lane = tid & 63;
  const int wave = tid >> 6;
  const int bm = blockIdx.y * 128;
  const int bn = blockIdx.x * 128;
  const int wm = (wave & 1) * 64;
  const int wn = (wave >> 1) * 64;
  const int quad = lane >> 4;
  const int l16  = lane & 15;

  constexpr int SMEM_BYTES = VSPLIT ? (128 * 136 * 2) : (128 * 64 * 2 * 2);
  __shared__ __align__(16) char smem[SMEM_BYTES];
  __hip_bfloat16* As = reinterpret_cast<__hip_bfloat16*>(smem);
  __hip_bfloat16* Bs = reinterpret_cast<__hip_bfloat16*>(smem + 128 * 64 * 2);

  floatx4 acc[4][4];
  #pragma unroll
  for (int i = 0; i < 4; i++)
    #pragma unroll
    for (int j = 0; j < 4; j++) {
      floatx4 z = {0.f, 0.f, 0.f, 0.f};
      acc[i][j] = z;
    }

  const int srow = tid >> 3;
  const int sq   = tid & 7;
  const int sc8  = (sq ^ (srow & 7)) * 8;
  const __hip_bfloat16* Ab = A  + (size_t)(bm + srow) * K + sc8;
  const __hip_bfloat16* Bb = Bt + (size_t)(bn + srow) * K + sc8;

  const int axr = l16 & 7;

  for (int k0 = 0; k0 < K; k0 += 64) {
    __syncthreads();
    #pragma unroll
    for (int p = 0; p < 4; p++) {
      gld_lds16(Ab + (size_t)(p * 32) * K + k0, (char*)As + p * 4096 + tid * 16);
      gld_lds16(Bb + (size_t)(p * 32) * K + k0, (char*)Bs + p * 4096 + tid * 16);
    }
    __syncthreads();
    #pragma unroll
    for (int s0 = 0; s0 < 2; s0++) {
      const int qo = ((s0 * 4 + quad) ^ axr) * 8;
      short8 af[4], bfr[4];
      #pragma unroll
      for (int i = 0; i < 4; i++)
        af[i] = *reinterpret_cast<const short8*>(As + (wm + i * 16 + l16) * 64 + qo);
      #pragma unroll
      for (int j = 0; j < 4; j++)
        bfr[j] = *reinterpret_cast<const short8*>(Bs + (wn + j * 16 + l16) * 64 + qo);
      #pragma unroll
      for (int i = 0; i < 4; i++)
        #pragma unroll
        for (int j = 0; j < 4; j++)
          acc[i][j] = __builtin_amdgcn_mfma_f32_16x16x32_bf16(af[i], bfr[j], acc[i][j], 0, 0, 0);
    }
  }

  if constexpr (VSPLIT) {
    if (bn >= 2048) {
      // V third: bounce the transposed tile through LDS, then coalesced store
      // into vT[((b*16+h)*64+dh)*2048 + l].
      __syncthreads();                      // all waves done reading As/Bs
      unsigned short* T = reinterpret_cast<unsigned short*>(smem);  // [128][136]
      #pragma unroll
      for (int i = 0; i < 4; i++) {
        const int l = wm + i * 16 + quad * 4;      // 4 consecutive l per lane
        #pragma unroll
        for (int j = 0; j < 4; j++) {
          const int col = wn + j * 16 + l16;       // local v-col (h*64+dh)
          uint2 o;
          o.x = pack_bf16(acc[i][j][0], acc[i][j][1]);
          o.y = pack_bf16(acc[i][j][2], acc[i][j][3]);
          *reinterpret_cast<uint2*>(T + col * 136 + l) = o;
        }
      }
      __syncthreads();
      const int b  = bm >> 11;                     // batch
      const int l0 = bm & 2047;                    // token base within sequence
      const int h0 = (bn - 2048) >> 6;             // first of this block's 2 heads
      #pragma unroll
      for (int it = 0; it < 8; it++) {
        const int cid = it * 256 + tid;            // 0..2047
        const int col = cid >> 4;                  // 0..127
        const int ch  = cid & 15;                  // 16B chunk along l
        const short8 v = *reinterpret_cast<const short8*>(T + col * 136 + ch * 8);
        const int hh = h0 + (col >> 6);
        const int dh = col & 63;
        *reinterpret_cast<short8*>(
            vT + ((size_t)(b * NH + hh) * DH + dh) * LSEQ + l0 + ch * 8) = v;
      }
      return;
    }
  }

  #pragma unroll
  for (int i = 0; i < 4; i++)
    #pragma unroll
    for (int j = 0; j < 4; j++) {
      const int row0 = bm + wm + i * 16 + quad * 4;
      const int col  = bn + wn + j * 16 + l16;
      #pragma unroll
      for (int r = 0; r < 4; r++) {
        if constexpr (std::is_same<OutT, __hip_bfloat16>::value)
          C[(size_t)(row0 + r) * N + col] = __float2bfloat16(acc[i][j][r]);
        else
          C[(size_t)(row0 + r) * N + col] = acc[i][j][r];
      }
    }
}

// ---------------------------------------------------------------- fused rope (Q/K only)
// V is written transposed by gemm1's epilogue (VSPLIT) — the old vtrans blocks
// (2048..4095) are gone; grid is now 2048 blocks.
__global__ __launch_bounds__(256)
void ropevt_kernel(const unsigned short* __restrict__ qkv, const float* __restrict__ qw,
                   const float* __restrict__ kw, unsigned short* __restrict__ qT,
                   unsigned short* __restrict__ kT) {
  const int blk = blockIdx.x;
  const int tid = threadIdx.x;

  const int lane = tid & 63;
  const int t = blk * 4 + (tid >> 6);
  const int b = t >> 11, l = t & 2047;
  const unsigned short* row = qkv + (size_t)t * K3;
  const int hh = lane >> 2;
  const int jb = (lane & 3) * 8;
  const int base = hh * 64 + jb;

  const short8 qa_u = *reinterpret_cast<const short8*>(row + base);
  const short8 qb_u = *reinterpret_cast<const short8*>(row + base + 32);
  const short8 ka_u = *reinterpret_cast<const short8*>(row + 1024 + base);
  const short8 kb_u = *reinterpret_cast<const short8*>(row + 1024 + base + 32);

  float qa[8], qb[8], ka[8], kb[8];
  float s_q = 0.f, ss_q = 0.f, s_k = 0.f, ss_k = 0.f;
  #pragma unroll
  for (int e = 0; e < 8; e++) {
    qa[e] = bf2f((unsigned short)qa_u[e]); qb[e] = bf2f((unsigned short)qb_u[e]);
    ka[e] = bf2f((unsigned short)ka_u[e]); kb[e] = bf2f((unsigned short)kb_u[e]);
    s_q  += qa[e] + qb[e];  ss_q += qa[e]*qa[e] + qb[e]*qb[e];
    s_k  += ka[e] + kb[e];  ss_k += ka[e]*ka[e] + kb[e]*kb[e];
  }
  #pragma unroll
  for (int off = 1; off < 64; off <<= 1) {
    s_q  += __shfl_xor(s_q, off);  ss_q += __shfl_xor(ss_q, off);
    s_k  += __shfl_xor(s_k, off);  ss_k += __shfl_xor(ss_k, off);
  }
  const float qmu = s_q * (1.f/1024);
  const float qrs = rsqrtf(ss_q * (1.f/1024) - qmu*qmu + 1e-5f);
  const float kmu = s_k * (1.f/1024);
  const float krs = rsqrtf(ss_k * (1.f/1024) - kmu*kmu + 1e-5f);

  const int j0 = lane & 31;
  const float invf = __expf(-(float)j0 * 0.28782313662425575f);   // ln(1e4)/32
  float tsin, tcos;
  sincosf((float)l * invf, &tsin, &tcos);

  const float4 wq0 = *reinterpret_cast<const float4*>(qw + base);
  const float4 wq1 = *reinterpret_cast<const float4*>(qw + base + 4);
  const float4 wq2 = *reinterpret_cast<const float4*>(qw + base + 32);
  const float4 wq3 = *reinterpret_cast<const float4*>(qw + base + 36);
  const float4 wk0 = *reinterpret_cast<const float4*>(kw + base);
  const float4 wk1 = *reinterpret_cast<const float4*>(kw + base + 4);
  const float4 wk2 = *reinterpret_cast<const float4*>(kw + base + 32);
  const float4 wk3 = *reinterpret_cast<const float4*>(kw + base + 36);
  const float wqa[8] = {wq0.x,wq0.y,wq0.z,wq0.w, wq1.x,wq1.y,wq1.z,wq1.w};
  const float wqb[8] = {wq2.x,wq2.y,wq2.z,wq2.w, wq3.x,wq3.y,wq3.z,wq3.w};
  const float wka[8] = {wk0.x,wk0.y,wk0.z,wk0.w, wk1.x,wk1.y,wk1.z,wk1.w};
  const float wkb[8] = {wk2.x,wk2.y,wk2.z,wk2.w, wk3.x,wk3.y,wk3.z,wk3.w};

  short8 oqa, oqb, oka, okb;
  #pragma unroll
  for (int e = 0; e < 8; e++) {
    const int j = jb + e;
    const float c  = __shfl(tcos, j);
    const float sn = __shfl(tsin, j);
    const float qn1 = (qa[e] - qmu) * qrs * wqa[e];
    const float qn2 = (qb[e] - qmu) * qrs * wqb[e];
    const float kn1 = (ka[e] - kmu) * krs * wka[e];
    const float kn2 = (kb[e] - kmu) * krs * wkb[e];
    oqa[e] = (short)f2bf_bits((qn1 * c - qn2 * sn) * 0.125f);
    oqb[e] = (short)f2bf_bits((qn2 * c + qn1 * sn) * 0.125f);
    oka[e] = (short)f2bf_bits(kn1 * c - kn2 * sn);
    okb[e] = (short)f2bf_bits(kn2 * c + kn1 * sn);
  }
  const size_t ob = ((size_t)(b * NH + hh) * LSEQ + l) * DH + jb;
  *reinterpret_cast<short8*>(qT + ob)      = oqa;
  *reinterpret_cast<short8*>(qT + ob + 32) = oqb;
  *reinterpret_cast<short8*>(kT + ob)      = oka;
  *reinterpret_cast<short8*>(kT + ob + 32) = okb;
}

// ---------------------------------------------------------------- MFMA flash attention
// r6 (best-measured) verbatim: LDS-staged K/V lockstep, stride-72 padded LDS,
// watermark softmax (m=9 init; common path has no cross-lane max / no rescale /
// no p-guards; rare __any(vm>m) path is exact online-softmax).
__global__ __launch_bounds__(256)
void attn_mfma(const unsigned short* __restrict__ qT, const unsigned short* __restrict__ kT,
               const unsigned short* __restrict__ vT, const int* __restrict__ segs,
               const int* __restrict__ sege, unsigned short* __restrict__ ctx) {
  const int tid  = threadIdx.x;
  const int lane = tid & 63, w = tid >> 6;
  const int quad = lane >> 4, l16 = lane & 15;
  const int qbase = blockIdx.x * 128;
  const int h = blockIdx.y, b = blockIdx.z;
  const size_t bh = (size_t)(b * NH + h);
  const unsigned short* Kg = kT + bh * LSEQ * DH;
  const unsigned short* Vg = vT + bh * DH * LSEQ;

  __shared__ __align__(16) unsigned short Ks[64 * 72];
  __shared__ __align__(16) unsigned short Vs[64 * 72];
  __shared__ __align__(16) unsigned short Ps[4][32 * 72];

  short8 qf[2][2];
  int st[2], en[2];
  #pragma unroll
  for (int g = 0; g < 2; g++) {
    const int qy = qbase + w * 32 + g * 16 + l16;
    const unsigned short* Qrow = qT + (bh * LSEQ + qy) * DH;
    qf[g][0] = *reinterpret_cast<const short8*>(Qrow + quad * 8);
    qf[g][1] = *reinterpret_cast<const short8*>(Qrow + 32 + quad * 8);
    st[g] = segs[b * LSEQ + qy];
    en[g] = sege[b * LSEQ + qy];
  }

  const int kmin = segs[b * LSEQ + qbase] & ~63;
  const int kmax = sege[b * LSEQ + qbase + 127];
  const int wmin = segs[b * LSEQ + qbase + w * 32];
  const int wmax = sege[b * LSEQ + qbase + w * 32 + 31];
  int gmin[2], gmax[2];
  #pragma unroll
  for (int g = 0; g < 2; g++) {
    gmin[g] = segs[b * LSEQ + qbase + w * 32 + g * 16];
    gmax[g] = sege[b * LSEQ + qbase + w * 32 + g * 16 + 15];
  }

  floatx4 acc[2][4];
  #pragma unroll
  for (int g = 0; g < 2; g++)
    #pragma unroll
    for (int dt = 0; dt < 4; dt++) { floatx4 z = {0.f,0.f,0.f,0.f}; acc[g][dt] = z; }
  float m[2] = {9.f, 9.f};          // watermark; rare path handles exceedance
  float lsum[2] = {0.f, 0.f};       // per-lane partials; quad-reduced at end

  const int r_ = tid >> 3, c_ = (tid & 7) * 8;

  for (int kk = kmin; kk < kmax; kk += 64) {
    __syncthreads();
    #pragma unroll
    for (int it = 0; it < 2; it++) {
      const int r = r_ + it * 32;
      *reinterpret_cast<short8*>(Ks + r * 72 + c_) =
          *reinterpret_cast<const short8*>(Kg + (size_t)(kk + r) * DH + c_);
      *reinterpret_cast<short8*>(Vs + r * 72 + c_) =
          *reinterpret_cast<const short8*>(Vg + (size_t)r * LSEQ + kk + c_);
    }
    __syncthreads();

    if (kk + 64 <= wmin || kk >= wmax) continue;   // tile outside this wave's 32-query span

    bool act[2];
    #pragma unroll
    for (int g = 0; g < 2; g++) {
      act[g] = !(kk + 64 <= gmin[g] || kk >= gmax[g]);
      if (!act[g]) continue;

      // S^T = K Q^T for this group's 16 queries
      floatx4 sc[4];
      #pragma unroll
      for (int t = 0; t < 4; t++) {
        const short8 kf0 = *reinterpret_cast<const short8*>(Ks + (t * 16 + l16) * 72 + quad * 8);
        const short8 kf1 = *reinterpret_cast<const short8*>(Ks + (t * 16 + l16) * 72 + 32 + quad * 8);
        floatx4 z = {0.f,0.f,0.f,0.f};
        sc[t] = __builtin_amdgcn_mfma_f32_16x16x32_bf16(kf0, qf[g][0], z, 0, 0, 0);
        sc[t] = __builtin_amdgcn_mfma_f32_16x16x32_bf16(kf1, qf[g][1], sc[t], 0, 0, 0);
      }

      const unsigned span = (unsigned)(en[g] - st[g]);
      float vm = -1e30f;
      #pragma unroll
      for (int t = 0; t < 4; t++) {
        const int k0 = kk + t * 16 + quad * 4;
        #pragma unroll
        for (int r = 0; r < 4; r++) {
          const bool ok = (unsigned)(k0 + r - st[g]) < span;
          sc[t][r] = ok ? sc[t][r] : -1e30f;
          vm = fmaxf(vm, sc[t][r]);
        }
      }

      // rare path: watermark exceeded -> full exact online-softmax rescale
      if (__any(vm > m[g])) {
        float vv = fmaxf(vm, __shfl_xor(vm, 16));
        vv = fmaxf(vv, __shfl_xor(vv, 32));       // wave-uniform new max (> m)
        const float a = __expf(m[g] - vv);
        lsum[g] *= a;
        #pragma unroll
        for (int dt = 0; dt < 4; dt++)
          #pragma unroll
          for (int r = 0; r < 4; r++) acc[g][dt][r] *= a;
        m[g] = vv;
      }

      const float mn = m[g];
      float rs = 0.f;
      #pragma unroll
      for (int t = 0; t < 4; t++) {
        const float p0 = __expf(sc[t][0] - mn);   // exp(-1e30-mn) == 0: masked
        const float p1 = __expf(sc[t][1] - mn);
        const float p2 = __expf(sc[t][2] - mn);
        const float p3 = __expf(sc[t][3] - mn);
        rs += (p0 + p1) + (p2 + p3);
        uint2 pk;
        pk.x = pack_bf16(p0, p1);
        pk.y = pack_bf16(p2, p3);
        *reinterpret_cast<uint2*>(&Ps[w][(g * 16 + l16) * 72 + t * 16 + quad * 4]) = pk;
      }
      lsum[g] += rs;                               // per-lane partial (no shfl)
    }

    // read P for both groups, then shared V fragments feed both PV updates
    short8 pf[2][2];
    #pragma unroll
    for (int g = 0; g < 2; g++) {
      if (!act[g]) continue;
      pf[g][0] = *reinterpret_cast<const short8*>(&Ps[w][(g * 16 + l16) * 72 + quad * 8]);
      pf[g][1] = *reinterpret_cast<const short8*>(&Ps[w][(g * 16 + l16) * 72 + 32 + quad * 8]);
    }
    #pragma unroll
    for (int dt = 0; dt < 4; dt++) {
      const short8 vf0 = *reinterpret_cast<const short8*>(Vs + (dt * 16 + l16) * 72 + quad * 8);
      const short8 vf1 = *reinterpret_cast<const short8*>(Vs + (dt * 16 + l16) * 72 + 32 + quad * 8);
      #pragma unroll
      for (int g = 0; g < 2; g++) {
        if (!act[g]) continue;
        // no alpha-rescale here: rare path rescaled acc in place
        acc[g][dt] = __builtin_amdgcn_mfma_f32_16x16x32_bf16(vf0, pf[g][0], acc[g][dt], 0, 0, 0);
        acc[g][dt] = __builtin_amdgcn_mfma_f32_16x16x32_bf16(vf1, pf[g][1], acc[g][dt], 0, 0, 0);
      }
    }
  }

  #pragma unroll
  for (int g = 0; g < 2; g++) {
    // deferred cross-quad lsum reduction (once per wave, not per tile)
    lsum[g] += __shfl_xor(lsum[g], 16);
    lsum[g] += __shfl_xor(lsum[g], 32);
    const float inv = (lsum[g] > 0.f) ? 1.f / lsum[g] : 0.f;
    const int qy = qbase + w * 32 + g * 16 + l16;
    unsigned short* orow = ctx + ((size_t)(b * LSEQ + qy)) * D_MODEL + h * DH;
    #pragma unroll
    for (int dt = 0; dt < 4; dt++) {
      uint2 o;
      o.x = pack_bf16(acc[g][dt][0] * inv, acc[g][dt][1] * inv);
      o.y = pack_bf16(acc[g][dt][2] * inv, acc[g][dt][3] * inv);
      *reinterpret_cast<uint2*>(orow + dt * 16 + quad * 4) = o;
    }
  }
}

// ---------------------------------------------------------------- launch
extern "C" void kernel_launch(void* const* d_in, const int* in_sizes, int n_in,
                              void* d_out, int out_size, void* d_ws, size_t ws_size,
                              hipStream_t stream) {
  const float* x      = (const float*)d_in[0];
  const int*   sid    = (const int*)d_in[1];
  const float* ln_w   = (const float*)d_in[2];
  const float* ln_b   = (const float*)d_in[3];
  const float* w_qkv  = (const float*)d_in[4];
  const float* q_ln_w = (const float*)d_in[5];
  const float* k_ln_w = (const float*)d_in[6];
  const float* w_out  = (const float*)d_in[7];
  float* out = (float*)d_out;
  char* ws = (char*)d_ws;

  constexpr size_t OFF_WQKVT = 0;                        //  6,291,456
  constexpr size_t OFF_WOUTT = 6291456;                  //  2,097,152
  constexpr size_t OFF_H     = 8388608;                  // 16,777,216
  constexpr size_t OFF_QKV   = 25165824;                 // 50,331,648 (bf16)
  constexpr size_t OFF_QT    = 75497472;                 // 16,777,216
  constexpr size_t OFF_KT    = 92274688;                 // 16,777,216
  constexpr size_t OFF_VT    = 109051904;                // 16,777,216
  constexpr size_t OFF_CTX   = 125829120;                // 16,777,216
  constexpr size_t OFF_SEGS  = 142606336;                // 32,768
  constexpr size_t OFF_SEGE  = 142639104;                // 32,768

  __hip_bfloat16* wqkvT = (__hip_bfloat16*)(ws + OFF_WQKVT);
  __hip_bfloat16* woutT = (__hip_bfloat16*)(ws + OFF_WOUTT);
  __hip_bfloat16* hbuf  = (__hip_bfloat16*)(ws + OFF_H);
  __hip_bfloat16* qkvb  = (__hip_bfloat16*)(ws + OFF_QKV);
  unsigned short* qTb   = (unsigned short*)(ws + OFF_QT);
  unsigned short* kTb   = (unsigned short*)(ws + OFF_KT);
  unsigned short* vTb   = (unsigned short*)(ws + OFF_VT);
  unsigned short* ctx   = (unsigned short*)(ws + OFF_CTX);
  int*            segst = (int*)(ws + OFF_SEGS);
  int*            segen = (int*)(ws + OFF_SEGE);

  prep_kernel<<<6176, 256, 0, stream>>>(x, ln_w, ln_b, w_qkv, w_out, sid,
                                        hbuf, wqkvT, woutT, segst, segen);
  gemm_bt<__hip_bfloat16, true><<<dim3(K3 / 128, NTOK / 128), 256, 0, stream>>>(
      hbuf, wqkvT, qkvb, vTb, NTOK, K3, 1024);
  ropevt_kernel<<<2048, 256, 0, stream>>>((const unsigned short*)qkvb, q_ln_w, k_ln_w,
                                          qTb, kTb);
  attn_mfma<<<dim3(LSEQ / 128, NH, BATCH), 256, 0, stream>>>(qTb, kTb, vTb, segst, segen, ctx);
  gemm_bt<float, false><<<dim3(D_MODEL / 128, NTOK / 128), 256, 0, stream>>>(
      (const __hip_bfloat16*)ctx, woutT, out, nullptr, NTOK, D_MODEL, 1024);
}

// Round 12
// 230.494 us; speedup vs baseline: 1.1652x; 1.0040x over previous
//
#include <hip/hip_runtime.h>
#include <hip/hip_bf16.h>
#include <cstdint>
#include <cstddef>
#include <type_traits>

#define D_MODEL 1024
#define NH      16
#define DH      64
#define LSEQ    2048
#define BATCH   4
#define NTOK    8192      // BATCH * LSEQ
#define K3      3072

typedef __attribute__((ext_vector_type(8))) short  short8;
typedef __attribute__((ext_vector_type(4))) float  floatx4;

__device__ __forceinline__ unsigned short f2bf_bits(float f) {
  __hip_bfloat16 h = __float2bfloat16(f);
  return __builtin_bit_cast(unsigned short, h);
}
__device__ __forceinline__ float bf2f(unsigned short u) {
  return __bfloat162float(__builtin_bit_cast(__hip_bfloat16, u));
}
__device__ __forceinline__ unsigned int pack_bf16(float lo, float hi) {
  return (unsigned int)f2bf_bits(lo) | ((unsigned int)f2bf_bits(hi) << 16);
}

__device__ __forceinline__ void gld_lds16(const void* g, void* l) {
  __builtin_amdgcn_global_load_lds(
      (const __attribute__((address_space(1))) void*)g,
      (__attribute__((address_space(3))) void*)l,
      16, 0, 0);
}

// ---------------------------------------------------------------- fused prologue
// blocks [0,3072): transpose+cast w_qkv [1024][3072] -> wqkvT [3072][1024]
// blocks [3072,4096): transpose+cast w_out [1024][1024] -> woutT
// blocks [4096,6144): LayerNorm(x) -> hbuf (4 tokens/block, wave per token)
// blocks [6144,6176): segment bounds
// Transpose store phase: one packed uint2 (4 bf16) per thread instead of 8
// scalar 2B stores (8x fewer store insts; LDS gather is bank-conflict-free:
// within an 8-lane group banks step by 4).
__global__ __launch_bounds__(256)
void prep_kernel(const float* __restrict__ x, const float* __restrict__ ln_w,
                 const float* __restrict__ ln_b, const float* __restrict__ w_qkv,
                 const float* __restrict__ w_out, const int* __restrict__ sid,
                 __hip_bfloat16* __restrict__ hbuf, __hip_bfloat16* __restrict__ wqkvT,
                 __hip_bfloat16* __restrict__ woutT, int* __restrict__ segstart,
                 int* __restrict__ segend) {
  __shared__ __align__(16) char smem[8448];
  const int blk = blockIdx.x;
  const int tid = threadIdx.x;

  if (blk < 4096) {
    float (*tile)[33] = reinterpret_cast<float(*)[33]>(smem);
    const float* src;  __hip_bfloat16* dst;  int R, C, bx, by;
    if (blk < 3072) { src = w_qkv; dst = wqkvT; R = 1024; C = 3072; bx = blk % 96; by = blk / 96; }
    else            { src = w_out; dst = woutT; R = 1024; C = 1024; bx = (blk - 3072) & 31; by = (blk - 3072) >> 5; }
    const int c0 = bx * 32, r0 = by * 32;
    const int xx = tid & 31, yy = tid >> 5;   // 32 x 8
    #pragma unroll
    for (int j = 0; j < 32; j += 8)
      tile[yy + j][xx] = src[(size_t)(r0 + yy + j) * C + c0 + xx];
    __syncthreads();
    {
      const int cc = tid >> 3, ch = tid & 7;   // col 0..31, 4-row chunk 0..7
      uint2 o;
      o.x = pack_bf16(tile[ch * 4 + 0][cc], tile[ch * 4 + 1][cc]);
      o.y = pack_bf16(tile[ch * 4 + 2][cc], tile[ch * 4 + 3][cc]);
      *reinterpret_cast<uint2*>(&dst[(size_t)(c0 + cc) * R + r0 + ch * 4]) = o;
    }
  } else if (blk < 6144) {
    const int lane = tid & 63;
    const int t = (blk - 4096) * 4 + (tid >> 6);
    const float4* xr = reinterpret_cast<const float4*>(x) + (size_t)t * 256;
    float4 v[4];
    float s = 0.f, ss = 0.f;
    #pragma unroll
    for (int i = 0; i < 4; i++) {
      v[i] = xr[lane + i * 64];
      s  += (v[i].x + v[i].y) + (v[i].z + v[i].w);
      ss += (v[i].x*v[i].x + v[i].y*v[i].y) + (v[i].z*v[i].z + v[i].w*v[i].w);
    }
    #pragma unroll
    for (int off = 1; off < 64; off <<= 1) {
      s  += __shfl_xor(s, off);
      ss += __shfl_xor(ss, off);
    }
    const float mu = s * (1.f / 1024);
    const float rs = rsqrtf(ss * (1.f / 1024) - mu * mu + 1e-5f);
    const float4* wr = reinterpret_cast<const float4*>(ln_w);
    const float4* br = reinterpret_cast<const float4*>(ln_b);
    ushort4* hr = reinterpret_cast<ushort4*>(hbuf) + (size_t)t * 256;
    #pragma unroll
    for (int i = 0; i < 4; i++) {
      const float4 wv = wr[lane + i * 64];
      const float4 bv = br[lane + i * 64];
      ushort4 o;
      o.x = f2bf_bits((v[i].x - mu) * rs * wv.x + bv.x);
      o.y = f2bf_bits((v[i].y - mu) * rs * wv.y + bv.y);
      o.z = f2bf_bits((v[i].z - mu) * rs * wv.z + bv.z);
      o.w = f2bf_bits((v[i].w - mu) * rs * wv.w + bv.w);
      hr[lane + i * 64] = o;
    }
  } else {
    int* srow = reinterpret_cast<int*>(smem);
    const int sblk = blk - 6144;            // 0..31, 8 per batch
    const int b = sblk >> 3;
    const int* row = sid + (size_t)b * LSEQ;
    #pragma unroll
    for (int i = 0; i < 8; i++) srow[tid + i * 256] = row[tid + i * 256];
    __syncthreads();
    const int l = (sblk & 7) * 256 + tid;
    const int v = srow[l];
    int lo = 0, hi = l;
    while (lo < hi) { int mid = (lo + hi) >> 1; if (srow[mid] < v) lo = mid + 1; else hi = mid; }
    const int i = b * LSEQ + l;
    segstart[i] = lo;
    lo = l + 1; hi = LSEQ;
    while (lo < hi) { int mid = (lo + hi) >> 1; if (srow[mid] <= v) lo = mid + 1; else hi = mid; }
    segend[i] = lo;
  }
}

// ---------------------------------------------------------------- bf16 GEMM, Bt layout
// BK=64, XOR-swizzled LDS (conflict-free). launch_bounds(256,2): measured best.
// VSPLIT (gemm1 only): blocks with bn>=2048 compute the V third of qkv and
// write it DIRECTLY in vT's [b,h,dh,l] transposed layout, bounced through an
// LDS tile T[128 cols][136] so the global stores are 256B-coalesced segments.
template <typename OutT, bool VSPLIT>
__global__ __launch_bounds__(256, 2)
void gemm_bt(const __hip_bfloat16* __restrict__ A, const __hip_bfloat16* __restrict__ Bt,
             OutT* __restrict__ C, unsigned short* __restrict__ vT,
             int M, int N, int K) {
  const int tid  = threadIdx.x;
  const int lane = tid & 63;
  const int wave = tid >> 6;
  const int bm = blockIdx.y * 128;
  const int bn = blockIdx.x * 128;
  const int wm = (wave & 1) * 64;
  const int wn = (wave >> 1) * 64;
  const int quad = lane >> 4;
  const int l16  = lane & 15;

  constexpr int SMEM_BYTES = VSPLIT ? (128 * 136 * 2) : (128 * 64 * 2 * 2);
  __shared__ __align__(16) char smem[SMEM_BYTES];
  __hip_bfloat16* As = reinterpret_cast<__hip_bfloat16*>(smem);
  __hip_bfloat16* Bs = reinterpret_cast<__hip_bfloat16*>(smem + 128 * 64 * 2);

  floatx4 acc[4][4];
  #pragma unroll
  for (int i = 0; i < 4; i++)
    #pragma unroll
    for (int j = 0; j < 4; j++) {
      floatx4 z = {0.f, 0.f, 0.f, 0.f};
      acc[i][j] = z;
    }

  const int srow = tid >> 3;
  const int sq   = tid & 7;
  const int sc8  = (sq ^ (srow & 7)) * 8;
  const __hip_bfloat16* Ab = A  + (size_t)(bm + srow) * K + sc8;
  const __hip_bfloat16* Bb = Bt + (size_t)(bn + srow) * K + sc8;

  const int axr = l16 & 7;

  for (int k0 = 0; k0 < K; k0 += 64) {
    __syncthreads();
    #pragma unroll
    for (int p = 0; p < 4; p++) {
      gld_lds16(Ab + (size_t)(p * 32) * K + k0, (char*)As + p * 4096 + tid * 16);
      gld_lds16(Bb + (size_t)(p * 32) * K + k0, (char*)Bs + p * 4096 + tid * 16);
    }
    __syncthreads();
    #pragma unroll
    for (int s0 = 0; s0 < 2; s0++) {
      const int qo = ((s0 * 4 + quad) ^ axr) * 8;
      short8 af[4], bfr[4];
      #pragma unroll
      for (int i = 0; i < 4; i++)
        af[i] = *reinterpret_cast<const short8*>(As + (wm + i * 16 + l16) * 64 + qo);
      #pragma unroll
      for (int j = 0; j < 4; j++)
        bfr[j] = *reinterpret_cast<const short8*>(Bs + (wn + j * 16 + l16) * 64 + qo);
      #pragma unroll
      for (int i = 0; i < 4; i++)
        #pragma unroll
        for (int j = 0; j < 4; j++)
          acc[i][j] = __builtin_amdgcn_mfma_f32_16x16x32_bf16(af[i], bfr[j], acc[i][j], 0, 0, 0);
    }
  }

  if constexpr (VSPLIT) {
    if (bn >= 2048) {
      // V third: bounce the transposed tile through LDS, then coalesced store
      // into vT[((b*16+h)*64+dh)*2048 + l].
      __syncthreads();                      // all waves done reading As/Bs
      unsigned short* T = reinterpret_cast<unsigned short*>(smem);  // [128][136]
      #pragma unroll
      for (int i = 0; i < 4; i++) {
        const int l = wm + i * 16 + quad * 4;      // 4 consecutive l per lane
        #pragma unroll
        for (int j = 0; j < 4; j++) {
          const int col = wn + j * 16 + l16;       // local v-col (h*64+dh)
          uint2 o;
          o.x = pack_bf16(acc[i][j][0], acc[i][j][1]);
          o.y = pack_bf16(acc[i][j][2], acc[i][j][3]);
          *reinterpret_cast<uint2*>(T + col * 136 + l) = o;
        }
      }
      __syncthreads();
      const int b  = bm >> 11;                     // batch
      const int l0 = bm & 2047;                    // token base within sequence
      const int h0 = (bn - 2048) >> 6;             // first of this block's 2 heads
      #pragma unroll
      for (int it = 0; it < 8; it++) {
        const int cid = it * 256 + tid;            // 0..2047
        const int col = cid >> 4;                  // 0..127
        const int ch  = cid & 15;                  // 16B chunk along l
        const short8 v = *reinterpret_cast<const short8*>(T + col * 136 + ch * 8);
        const int hh = h0 + (col >> 6);
        const int dh = col & 63;
        *reinterpret_cast<short8*>(
            vT + ((size_t)(b * NH + hh) * DH + dh) * LSEQ + l0 + ch * 8) = v;
      }
      return;
    }
  }

  #pragma unroll
  for (int i = 0; i < 4; i++)
    #pragma unroll
    for (int j = 0; j < 4; j++) {
      const int row0 = bm + wm + i * 16 + quad * 4;
      const int col  = bn + wn + j * 16 + l16;
      #pragma unroll
      for (int r = 0; r < 4; r++) {
        if constexpr (std::is_same<OutT, __hip_bfloat16>::value)
          C[(size_t)(row0 + r) * N + col] = __float2bfloat16(acc[i][j][r]);
        else
          C[(size_t)(row0 + r) * N + col] = acc[i][j][r];
      }
    }
}

// ---------------------------------------------------------------- fused rope (Q/K only)
// qT/kT layout is now TOKEN-MAJOR: [b, l, h*64+dh] — identical to the qkv-row
// layout, so each wave's stores are one fully-contiguous 2KB row (the old
// head-major layout scattered 64B segments 256KB apart).
__global__ __launch_bounds__(256)
void ropevt_kernel(const unsigned short* __restrict__ qkv, const float* __restrict__ qw,
                   const float* __restrict__ kw, unsigned short* __restrict__ qT,
                   unsigned short* __restrict__ kT) {
  const int blk = blockIdx.x;
  const int tid = threadIdx.x;

  const int lane = tid & 63;
  const int t = blk * 4 + (tid >> 6);
  const int l = t & 2047;
  const unsigned short* row = qkv + (size_t)t * K3;
  const int hh = lane >> 2;
  const int jb = (lane & 3) * 8;
  const int base = hh * 64 + jb;

  const short8 qa_u = *reinterpret_cast<const short8*>(row + base);
  const short8 qb_u = *reinterpret_cast<const short8*>(row + base + 32);
  const short8 ka_u = *reinterpret_cast<const short8*>(row + 1024 + base);
  const short8 kb_u = *reinterpret_cast<const short8*>(row + 1024 + base + 32);

  float qa[8], qb[8], ka[8], kb[8];
  float s_q = 0.f, ss_q = 0.f, s_k = 0.f, ss_k = 0.f;
  #pragma unroll
  for (int e = 0; e < 8; e++) {
    qa[e] = bf2f((unsigned short)qa_u[e]); qb[e] = bf2f((unsigned short)qb_u[e]);
    ka[e] = bf2f((unsigned short)ka_u[e]); kb[e] = bf2f((unsigned short)kb_u[e]);
    s_q  += qa[e] + qb[e];  ss_q += qa[e]*qa[e] + qb[e]*qb[e];
    s_k  += ka[e] + kb[e];  ss_k += ka[e]*ka[e] + kb[e]*kb[e];
  }
  #pragma unroll
  for (int off = 1; off < 64; off <<= 1) {
    s_q  += __shfl_xor(s_q, off);  ss_q += __shfl_xor(ss_q, off);
    s_k  += __shfl_xor(s_k, off);  ss_k += __shfl_xor(ss_k, off);
  }
  const float qmu = s_q * (1.f/1024);
  const float qrs = rsqrtf(ss_q * (1.f/1024) - qmu*qmu + 1e-5f);
  const float kmu = s_k * (1.f/1024);
  const float krs = rsqrtf(ss_k * (1.f/1024) - kmu*kmu + 1e-5f);

  const int j0 = lane & 31;
  const float invf = __expf(-(float)j0 * 0.28782313662425575f);   // ln(1e4)/32
  float tsin, tcos;
  sincosf((float)l * invf, &tsin, &tcos);

  const float4 wq0 = *reinterpret_cast<const float4*>(qw + base);
  const float4 wq1 = *reinterpret_cast<const float4*>(qw + base + 4);
  const float4 wq2 = *reinterpret_cast<const float4*>(qw + base + 32);
  const float4 wq3 = *reinterpret_cast<const float4*>(qw + base + 36);
  const float4 wk0 = *reinterpret_cast<const float4*>(kw + base);
  const float4 wk1 = *reinterpret_cast<const float4*>(kw + base + 4);
  const float4 wk2 = *reinterpret_cast<const float4*>(kw + base + 32);
  const float4 wk3 = *reinterpret_cast<const float4*>(kw + base + 36);
  const float wqa[8] = {wq0.x,wq0.y,wq0.z,wq0.w, wq1.x,wq1.y,wq1.z,wq1.w};
  const float wqb[8] = {wq2.x,wq2.y,wq2.z,wq2.w, wq3.x,wq3.y,wq3.z,wq3.w};
  const float wka[8] = {wk0.x,wk0.y,wk0.z,wk0.w, wk1.x,wk1.y,wk1.z,wk1.w};
  const float wkb[8] = {wk2.x,wk2.y,wk2.z,wk2.w, wk3.x,wk3.y,wk3.z,wk3.w};

  short8 oqa, oqb, oka, okb;
  #pragma unroll
  for (int e = 0; e < 8; e++) {
    const int j = jb + e;
    const float c  = __shfl(tcos, j);
    const float sn = __shfl(tsin, j);
    const float qn1 = (qa[e] - qmu) * qrs * wqa[e];
    const float qn2 = (qb[e] - qmu) * qrs * wqb[e];
    const float kn1 = (ka[e] - kmu) * krs * wka[e];
    const float kn2 = (kb[e] - kmu) * krs * wkb[e];
    oqa[e] = (short)f2bf_bits((qn1 * c - qn2 * sn) * 0.125f);
    oqb[e] = (short)f2bf_bits((qn2 * c + qn1 * sn) * 0.125f);
    oka[e] = (short)f2bf_bits(kn1 * c - kn2 * sn);
    okb[e] = (short)f2bf_bits(kn2 * c + kn1 * sn);
  }
  const size_t ob = (size_t)t * 1024 + base;     // token-major: same row shape as input
  *reinterpret_cast<short8*>(qT + ob)      = oqa;
  *reinterpret_cast<short8*>(qT + ob + 32) = oqb;
  *reinterpret_cast<short8*>(kT + ob)      = oka;
  *reinterpret_cast<short8*>(kT + ob + 32) = okb;
}

// ---------------------------------------------------------------- MFMA flash attention
// r6 (best-measured) structure: LDS-staged K/V lockstep, stride-72 padded LDS,
// watermark softmax (m=9 init; common path has no cross-lane max / no rescale /
// no p-guards; rare __any(vm>m) path is exact online-softmax).
// qT/kT are TOKEN-MAJOR [b, l, h*64+dh]: Q/K row base = t*1024 + h*64, K-tile
// staging rows stride 1024 elems (2KB apart in L2 — fine). V stays [b,h,dh,l].
__global__ __launch_bounds__(256)
void attn_mfma(const unsigned short* __restrict__ qT, const unsigned short* __restrict__ kT,
               const unsigned short* __restrict__ vT, const int* __restrict__ segs,
               const int* __restrict__ sege, unsigned short* __restrict__ ctx) {
  const int tid  = threadIdx.x;
  const int lane = tid & 63, w = tid >> 6;
  const int quad = lane >> 4, l16 = lane & 15;
  const int qbase = blockIdx.x * 128;
  const int h = blockIdx.y, b = blockIdx.z;
  const size_t bh = (size_t)(b * NH + h);
  const unsigned short* Kg = kT + (size_t)b * LSEQ * 1024 + h * DH;  // token-major
  const unsigned short* Vg = vT + bh * DH * LSEQ;

  __shared__ __align__(16) unsigned short Ks[64 * 72];
  __shared__ __align__(16) unsigned short Vs[64 * 72];
  __shared__ __align__(16) unsigned short Ps[4][32 * 72];

  short8 qf[2][2];
  int st[2], en[2];
  #pragma unroll
  for (int g = 0; g < 2; g++) {
    const int qy = qbase + w * 32 + g * 16 + l16;
    const unsigned short* Qrow = qT + (size_t)(b * LSEQ + qy) * 1024 + h * DH;
    qf[g][0] = *reinterpret_cast<const short8*>(Qrow + quad * 8);
    qf[g][1] = *reinterpret_cast<const short8*>(Qrow + 32 + quad * 8);
    st[g] = segs[b * LSEQ + qy];
    en[g] = sege[b * LSEQ + qy];
  }

  const int kmin = segs[b * LSEQ + qbase] & ~63;
  const int kmax = sege[b * LSEQ + qbase + 127];
  const int wmin = segs[b * LSEQ + qbase + w * 32];
  const int wmax = sege[b * LSEQ + qbase + w * 32 + 31];
  int gmin[2], gmax[2];
  #pragma unroll
  for (int g = 0; g < 2; g++) {
    gmin[g] = segs[b * LSEQ + qbase + w * 32 + g * 16];
    gmax[g] = sege[b * LSEQ + qbase + w * 32 + g * 16 + 15];
  }

  floatx4 acc[2][4];
  #pragma unroll
  for (int g = 0; g < 2; g++)
    #pragma unroll
    for (int dt = 0; dt < 4; dt++) { floatx4 z = {0.f,0.f,0.f,0.f}; acc[g][dt] = z; }
  float m[2] = {9.f, 9.f};          // watermark; rare path handles exceedance
  float lsum[2] = {0.f, 0.f};       // per-lane partials; quad-reduced at end

  const int r_ = tid >> 3, c_ = (tid & 7) * 8;

  for (int kk = kmin; kk < kmax; kk += 64) {
    __syncthreads();
    #pragma unroll
    for (int it = 0; it < 2; it++) {
      const int r = r_ + it * 32;
      *reinterpret_cast<short8*>(Ks + r * 72 + c_) =
          *reinterpret_cast<const short8*>(Kg + (size_t)(kk + r) * 1024 + c_);
      *reinterpret_cast<short8*>(Vs + r * 72 + c_) =
          *reinterpret_cast<const short8*>(Vg + (size_t)r * LSEQ + kk + c_);
    }
    __syncthreads();

    if (kk + 64 <= wmin || kk >= wmax) continue;   // tile outside this wave's 32-query span

    bool act[2];
    #pragma unroll
    for (int g = 0; g < 2; g++) {
      act[g] = !(kk + 64 <= gmin[g] || kk >= gmax[g]);
      if (!act[g]) continue;

      // S^T = K Q^T for this group's 16 queries
      floatx4 sc[4];
      #pragma unroll
      for (int t = 0; t < 4; t++) {
        const short8 kf0 = *reinterpret_cast<const short8*>(Ks + (t * 16 + l16) * 72 + quad * 8);
        const short8 kf1 = *reinterpret_cast<const short8*>(Ks + (t * 16 + l16) * 72 + 32 + quad * 8);
        floatx4 z = {0.f,0.f,0.f,0.f};
        sc[t] = __builtin_amdgcn_mfma_f32_16x16x32_bf16(kf0, qf[g][0], z, 0, 0, 0);
        sc[t] = __builtin_amdgcn_mfma_f32_16x16x32_bf16(kf1, qf[g][1], sc[t], 0, 0, 0);
      }

      const unsigned span = (unsigned)(en[g] - st[g]);
      float vm = -1e30f;
      #pragma unroll
      for (int t = 0; t < 4; t++) {
        const int k0 = kk + t * 16 + quad * 4;
        #pragma unroll
        for (int r = 0; r < 4; r++) {
          const bool ok = (unsigned)(k0 + r - st[g]) < span;
          sc[t][r] = ok ? sc[t][r] : -1e30f;
          vm = fmaxf(vm, sc[t][r]);
        }
      }

      // rare path: watermark exceeded -> full exact online-softmax rescale
      if (__any(vm > m[g])) {
        float vv = fmaxf(vm, __shfl_xor(vm, 16));
        vv = fmaxf(vv, __shfl_xor(vv, 32));       // wave-uniform new max (> m)
        const float a = __expf(m[g] - vv);
        lsum[g] *= a;
        #pragma unroll
        for (int dt = 0; dt < 4; dt++)
          #pragma unroll
          for (int r = 0; r < 4; r++) acc[g][dt][r] *= a;
        m[g] = vv;
      }

      const float mn = m[g];
      float rs = 0.f;
      #pragma unroll
      for (int t = 0; t < 4; t++) {
        const float p0 = __expf(sc[t][0] - mn);   // exp(-1e30-mn) == 0: masked
        const float p1 = __expf(sc[t][1] - mn);
        const float p2 = __expf(sc[t][2] - mn);
        const float p3 = __expf(sc[t][3] - mn);
        rs += (p0 + p1) + (p2 + p3);
        uint2 pk;
        pk.x = pack_bf16(p0, p1);
        pk.y = pack_bf16(p2, p3);
        *reinterpret_cast<uint2*>(&Ps[w][(g * 16 + l16) * 72 + t * 16 + quad * 4]) = pk;
      }
      lsum[g] += rs;                               // per-lane partial (no shfl)
    }

    // read P for both groups, then shared V fragments feed both PV updates
    short8 pf[2][2];
    #pragma unroll
    for (int g = 0; g < 2; g++) {
      if (!act[g]) continue;
      pf[g][0] = *reinterpret_cast<const short8*>(&Ps[w][(g * 16 + l16) * 72 + quad * 8]);
      pf[g][1] = *reinterpret_cast<const short8*>(&Ps[w][(g * 16 + l16) * 72 + 32 + quad * 8]);
    }
    #pragma unroll
    for (int dt = 0; dt < 4; dt++) {
      const short8 vf0 = *reinterpret_cast<const short8*>(Vs + (dt * 16 + l16) * 72 + quad * 8);
      const short8 vf1 = *reinterpret_cast<const short8*>(Vs + (dt * 16 + l16) * 72 + 32 + quad * 8);
      #pragma unroll
      for (int g = 0; g < 2; g++) {
        if (!act[g]) continue;
        // no alpha-rescale here: rare path rescaled acc in place
        acc[g][dt] = __builtin_amdgcn_mfma_f32_16x16x32_bf16(vf0, pf[g][0], acc[g][dt], 0, 0, 0);
        acc[g][dt] = __builtin_amdgcn_mfma_f32_16x16x32_bf16(vf1, pf[g][1], acc[g][dt], 0, 0, 0);
      }
    }
  }

  #pragma unroll
  for (int g = 0; g < 2; g++) {
    // deferred cross-quad lsum reduction (once per wave, not per tile)
    lsum[g] += __shfl_xor(lsum[g], 16);
    lsum[g] += __shfl_xor(lsum[g], 32);
    const float inv = (lsum[g] > 0.f) ? 1.f / lsum[g] : 0.f;
    const int qy = qbase + w * 32 + g * 16 + l16;
    unsigned short* orow = ctx + ((size_t)(b * LSEQ + qy)) * D_MODEL + h * DH;
    #pragma unroll
    for (int dt = 0; dt < 4; dt++) {
      uint2 o;
      o.x = pack_bf16(acc[g][dt][0] * inv, acc[g][dt][1] * inv);
      o.y = pack_bf16(acc[g][dt][2] * inv, acc[g][dt][3] * inv);
      *reinterpret_cast<uint2*>(orow + dt * 16 + quad * 4) = o;
    }
  }
}

// ---------------------------------------------------------------- launch
extern "C" void kernel_launch(void* const* d_in, const int* in_sizes, int n_in,
                              void* d_out, int out_size, void* d_ws, size_t ws_size,
                              hipStream_t stream) {
  const float* x      = (const float*)d_in[0];
  const int*   sid    = (const int*)d_in[1];
  const float* ln_w   = (const float*)d_in[2];
  const float* ln_b   = (const float*)d_in[3];
  const float* w_qkv  = (const float*)d_in[4];
  const float* q_ln_w = (const float*)d_in[5];
  const float* k_ln_w = (const float*)d_in[6];
  const float* w_out  = (const float*)d_in[7];
  float* out = (float*)d_out;
  char* ws = (char*)d_ws;

  constexpr size_t OFF_WQKVT = 0;                        //  6,291,456
  constexpr size_t OFF_WOUTT = 6291456;                  //  2,097,152
  constexpr size_t OFF_H     = 8388608;                  // 16,777,216
  constexpr size_t OFF_QKV   = 25165824;                 // 50,331,648 (bf16)
  constexpr size_t OFF_QT    = 75497472;                 // 16,777,216
  constexpr size_t OFF_KT    = 92274688;                 // 16,777,216
  constexpr size_t OFF_VT    = 109051904;                // 16,777,216
  constexpr size_t OFF_CTX   = 125829120;                // 16,777,216
  constexpr size_t OFF_SEGS  = 142606336;                // 32,768
  constexpr size_t OFF_SEGE  = 142639104;                // 32,768

  __hip_bfloat16* wqkvT = (__hip_bfloat16*)(ws + OFF_WQKVT);
  __hip_bfloat16* woutT = (__hip_bfloat16*)(ws + OFF_WOUTT);
  __hip_bfloat16* hbuf  = (__hip_bfloat16*)(ws + OFF_H);
  __hip_bfloat16* qkvb  = (__hip_bfloat16*)(ws + OFF_QKV);
  unsigned short* qTb   = (unsigned short*)(ws + OFF_QT);
  unsigned short* kTb   = (unsigned short*)(ws + OFF_KT);
  unsigned short* vTb   = (unsigned short*)(ws + OFF_VT);
  unsigned short* ctx   = (unsigned short*)(ws + OFF_CTX);
  int*            segst = (int*)(ws + OFF_SEGS);
  int*            segen = (int*)(ws + OFF_SEGE);

  prep_kernel<<<6176, 256, 0, stream>>>(x, ln_w, ln_b, w_qkv, w_out, sid,
                                        hbuf, wqkvT, woutT, segst, segen);
  gemm_bt<__hip_bfloat16, true><<<dim3(K3 / 128, NTOK / 128), 256, 0, stream>>>(
      hbuf, wqkvT, qkvb, vTb, NTOK, K3, 1024);
  ropevt_kernel<<<2048, 256, 0, stream>>>((const unsigned short*)qkvb, q_ln_w, k_ln_w,
                                          qTb, kTb);
  attn_mfma<<<dim3(LSEQ / 128, NH, BATCH), 256, 0, stream>>>(qTb, kTb, vTb, segst, segen, ctx);
  gemm_bt<float, false><<<dim3(D_MODEL / 128, NTOK / 128), 256, 0, stream>>>(
      (const __hip_bfloat16*)ctx, woutT, out, nullptr, NTOK, D_MODEL, 1024);
}